// Round 8
// baseline (595.783 us; speedup 1.0000x reference)
//
#include <hip/hip_runtime.h>
#include <math.h>

// Problem constants (match reference)
#define T_TOK 2048   // B*L
#define SEQ   1024   // L
#define DM    1024   // d_model
#define DI    2048   // d_inner
#define FFN   4096
#define NST   16     // d_state
#define DTR   64     // dt_rank
#define XD    96     // dt_rank + 2*d_state
#define CHK   64     // scan chunk length
#define NCHK  16     // chunks per sequence
#define SPLITK 8     // x_proj K-splits (K chunk = 256)

typedef __attribute__((ext_vector_type(8))) short short8;
typedef __attribute__((ext_vector_type(4))) float floatx4;

__device__ __forceinline__ unsigned short f2b(float f) {
  unsigned u = __float_as_uint(f);
  unsigned r = (u + 0x7fff + ((u >> 16) & 1)) >> 16;  // RNE
  return (unsigned short)r;
}
__device__ __forceinline__ float b2f(unsigned short s) {
  return __uint_as_float(((unsigned)s) << 16);
}

// async global->LDS, 16 B per lane. lds must be the wave-uniform base
// (lane 0's destination); HW adds lane*16.
typedef const __attribute__((address_space(1))) unsigned int g_uint;
typedef __attribute__((address_space(3))) unsigned int l_uint;
__device__ __forceinline__ void async16(void* lds, const void* g) {
  __builtin_amdgcn_global_load_lds((g_uint*)(size_t)g,
                                   (l_uint*)(unsigned)(size_t)lds, 16, 0, 0);
}

// ---------------------------------------------------------------------------
// fp32 -> bf16 bulk convert (n multiple of 1024); 4 elems/thread
// ---------------------------------------------------------------------------
__global__ __launch_bounds__(256) void f2b_k(const float* __restrict__ in,
                                             unsigned short* __restrict__ out) {
  int i = blockIdx.x * 256 + threadIdx.x;
  float4 v = ((const float4*)in)[i];
  ushort4 o;
  o.x = f2b(v.x); o.y = f2b(v.y); o.z = f2b(v.z); o.w = f2b(v.w);
  ((ushort4*)out)[i] = o;
}

// two-tensor variant: converts a (na elems, na/1024 blocks) then b
__global__ __launch_bounds__(256) void f2b2_k(const float* __restrict__ a,
                                              unsigned short* __restrict__ oa,
                                              int na4,
                                              const float* __restrict__ b,
                                              unsigned short* __restrict__ ob) {
  int i = blockIdx.x * 256 + threadIdx.x;
  const float* in = (i < na4) ? a : b;
  unsigned short* out = (i < na4) ? oa : ob;
  int j = (i < na4) ? i : i - na4;
  float4 v = ((const float4*)in)[j];
  ushort4 o;
  o.x = f2b(v.x); o.y = f2b(v.y); o.z = f2b(v.z); o.w = f2b(v.w);
  ((ushort4*)out)[j] = o;
}

// ---------------------------------------------------------------------------
// Fused LN0+LN1: xout = LN0(x) fp32 (residual), uout = bf16(LN1(LN0(x)))
// one block per token, 256 threads x 4 elems = 1024 dims
// ---------------------------------------------------------------------------
__global__ __launch_bounds__(256) void ln01_k(
    const float* __restrict__ in, const float* __restrict__ w0,
    const float* __restrict__ b0, const float* __restrict__ w1,
    const float* __restrict__ b1, float* __restrict__ xout,
    unsigned short* __restrict__ uout) {
  int t = blockIdx.x, tid = threadIdx.x;
  int wv = tid >> 6, ln = tid & 63;
  __shared__ float sm[4][4];
  float4 v = *(const float4*)(in + (size_t)t * DM + tid * 4);
  float s = v.x + v.y + v.z + v.w;
  for (int o = 32; o > 0; o >>= 1) s += __shfl_down(s, o, 64);
  if (ln == 0) sm[0][wv] = s;
  __syncthreads();
  float mu = (sm[0][0] + sm[0][1] + sm[0][2] + sm[0][3]) * (1.0f / DM);
  float d0 = v.x - mu, d1 = v.y - mu, d2 = v.z - mu, d3 = v.w - mu;
  float sq = d0 * d0 + d1 * d1 + d2 * d2 + d3 * d3;
  for (int o = 32; o > 0; o >>= 1) sq += __shfl_down(sq, o, 64);
  if (ln == 0) sm[1][wv] = sq;
  __syncthreads();
  float rs = rsqrtf((sm[1][0] + sm[1][1] + sm[1][2] + sm[1][3]) * (1.0f / DM) + 1e-5f);
  float4 w4 = *(const float4*)(w0 + tid * 4);
  float4 b4 = *(const float4*)(b0 + tid * 4);
  float r0 = d0 * rs * w4.x + b4.x, r1 = d1 * rs * w4.y + b4.y;
  float r2 = d2 * rs * w4.z + b4.z, r3 = d3 * rs * w4.w + b4.w;
  *(float4*)(xout + (size_t)t * DM + tid * 4) = make_float4(r0, r1, r2, r3);
  // LN1 of r
  float s1 = r0 + r1 + r2 + r3;
  for (int o = 32; o > 0; o >>= 1) s1 += __shfl_down(s1, o, 64);
  if (ln == 0) sm[2][wv] = s1;
  __syncthreads();
  float mu1 = (sm[2][0] + sm[2][1] + sm[2][2] + sm[2][3]) * (1.0f / DM);
  float e0 = r0 - mu1, e1 = r1 - mu1, e2 = r2 - mu1, e3 = r3 - mu1;
  float sq1 = e0 * e0 + e1 * e1 + e2 * e2 + e3 * e3;
  for (int o = 32; o > 0; o >>= 1) sq1 += __shfl_down(sq1, o, 64);
  if (ln == 0) sm[3][wv] = sq1;
  __syncthreads();
  float rs1 = rsqrtf((sm[3][0] + sm[3][1] + sm[3][2] + sm[3][3]) * (1.0f / DM) + 1e-5f);
  float4 w14 = *(const float4*)(w1 + tid * 4);
  float4 b14 = *(const float4*)(b1 + tid * 4);
  ushort4 o;
  o.x = f2b(e0 * rs1 * w14.x + b14.x);
  o.y = f2b(e1 * rs1 * w14.y + b14.y);
  o.z = f2b(e2 * rs1 * w14.z + b14.z);
  o.w = f2b(e3 * rs1 * w14.w + b14.w);
  *(ushort4*)(uout + (size_t)t * DM + tid * 4) = o;
}

// LayerNorm bf16 out (standalone; kept for generality)
__global__ __launch_bounds__(256) void ln_bf_k(const float* __restrict__ in,
                                               const float* __restrict__ w,
                                               const float* __restrict__ bb,
                                               unsigned short* __restrict__ out) {
  int t = blockIdx.x;
  int tid = threadIdx.x;
  const float* row = in + (size_t)t * DM;
  float4 v = *(const float4*)(row + tid * 4);
  float s = v.x + v.y + v.z + v.w;
  __shared__ float sm[2][4];
  for (int off = 32; off > 0; off >>= 1) s += __shfl_down(s, off, 64);
  int wv = tid >> 6, ln = tid & 63;
  if (ln == 0) sm[0][wv] = s;
  __syncthreads();
  float mu = (sm[0][0] + sm[0][1] + sm[0][2] + sm[0][3]) * (1.0f / DM);
  float d0 = v.x - mu, d1 = v.y - mu, d2 = v.z - mu, d3 = v.w - mu;
  float sq = d0 * d0 + d1 * d1 + d2 * d2 + d3 * d3;
  for (int off = 32; off > 0; off >>= 1) sq += __shfl_down(sq, off, 64);
  if (ln == 0) sm[1][wv] = sq;
  __syncthreads();
  float var = (sm[1][0] + sm[1][1] + sm[1][2] + sm[1][3]) * (1.0f / DM);
  float rs = rsqrtf(var + 1e-5f);
  float4 w4 = *(const float4*)(w + tid * 4);
  float4 b4 = *(const float4*)(bb + tid * 4);
  ushort4 o;
  o.x = f2b(d0 * rs * w4.x + b4.x);
  o.y = f2b(d1 * rs * w4.y + b4.y);
  o.z = f2b(d2 * rs * w4.z + b4.z);
  o.w = f2b(d3 * rs * w4.w + b4.w);
  *(ushort4*)(out + (size_t)t * DM + tid * 4) = o;
}

// ---------------------------------------------------------------------------
// bf16 MFMA GEMM (NT): C[m,n] = sum_k A[m,k]*W[n,k].  128x128 tile, 4 waves
// (2x2), 16x16x32 MFMA, double-buffered global_load_lds staging (R7-proven).
// Split-K via blockIdx.z.
// epi: 0 fp32 | 1 bf16 | 2 gelu(acc+bias) bf16 | 3 acc+res fp32
//      4 acc+bias+res fp32 | 5 softplus(acc+bias) fp32
//      6 split-K fp32 partial (z01->p0, z23->p1) | 8 split-K bf16 partial in p0
// ---------------------------------------------------------------------------
__global__ __launch_bounds__(256) void gemm_bf16(
    const unsigned short* __restrict__ A, int lda,
    const unsigned short* __restrict__ Bw, int ldb,
    void* __restrict__ Cout, int ldc, int Kc, int epi,
    const float* __restrict__ bias, const float* __restrict__ res,
    float* __restrict__ p0, float* __restrict__ p1) {
  __shared__ __align__(16) unsigned short As[2][4][128][8];  // [buf][slab][row][8k]
  __shared__ __align__(16) unsigned short Bs[2][4][128][8];
  int tid = threadIdx.x;
  int lane = tid & 63, wv = tid >> 6;
  int wr = wv >> 1, wc = wv & 1;
  int m0 = blockIdx.y * 128, n0 = blockIdx.x * 128;
  int ml = lane & 15, kq = lane >> 4;
  int kstart = blockIdx.z * Kc;
  int niter = Kc / 32;
  int c0 = tid, c1 = tid + 256;
  int row_a = c0 & 127, slab_a = c0 >> 7;
  int row_b = c1 & 127, slab_b = c1 >> 7;
  int cw0 = wv * 64, cw1 = wv * 64 + 256;
  int row0a = cw0 & 127, slab0a = cw0 >> 7;
  int row0b = cw1 & 127, slab0b = cw1 >> 7;
  {
    int k0 = kstart;
    async16(&As[0][slab0a][row0a][0], A + (size_t)(m0 + row_a) * lda + k0 + slab_a * 8);
    async16(&Bs[0][slab0a][row0a][0], Bw + (size_t)(n0 + row_a) * ldb + k0 + slab_a * 8);
    async16(&As[0][slab0b][row0b][0], A + (size_t)(m0 + row_b) * lda + k0 + slab_b * 8);
    async16(&Bs[0][slab0b][row0b][0], Bw + (size_t)(n0 + row_b) * ldb + k0 + slab_b * 8);
  }
  floatx4 acc[4][4] = {};
  for (int it = 0; it < niter; ++it) {
    __syncthreads();
    int cur = it & 1;
    if (it + 1 < niter) {
      int k0 = kstart + (it + 1) * 32;
      int nb = cur ^ 1;
      async16(&As[nb][slab0a][row0a][0], A + (size_t)(m0 + row_a) * lda + k0 + slab_a * 8);
      async16(&Bs[nb][slab0a][row0a][0], Bw + (size_t)(n0 + row_a) * ldb + k0 + slab_a * 8);
      async16(&As[nb][slab0b][row0b][0], A + (size_t)(m0 + row_b) * lda + k0 + slab_b * 8);
      async16(&Bs[nb][slab0b][row0b][0], Bw + (size_t)(n0 + row_b) * ldb + k0 + slab_b * 8);
    }
    short8 af[4], bfr[4];
#pragma unroll
    for (int i = 0; i < 4; ++i)
      af[i] = *(const short8*)&As[cur][kq][wr * 64 + i * 16 + ml][0];
#pragma unroll
    for (int j = 0; j < 4; ++j)
      bfr[j] = *(const short8*)&Bs[cur][kq][wc * 64 + j * 16 + ml][0];
#pragma unroll
    for (int i = 0; i < 4; ++i)
#pragma unroll
      for (int j = 0; j < 4; ++j)
        acc[i][j] =
            __builtin_amdgcn_mfma_f32_16x16x32_bf16(af[i], bfr[j], acc[i][j], 0, 0, 0);
  }
  float* pdst = nullptr;
  unsigned short* pdstb = nullptr;
  if (epi == 6) {
    pdst = (blockIdx.z & 2) ? p1 : p0;
    pdst += (size_t)(blockIdx.z & 1) * T_TOK * ldc;
  } else if (epi == 8) {
    pdstb = (unsigned short*)p0 + (size_t)blockIdx.z * T_TOK * ldc;
  }
  // epilogue: D row = (lane>>4)*4 + r, col = lane&15
#pragma unroll
  for (int i = 0; i < 4; ++i) {
    int gm = m0 + wr * 64 + i * 16 + kq * 4;
#pragma unroll
    for (int j = 0; j < 4; ++j) {
      int gn = n0 + wc * 64 + j * 16 + ml;
#pragma unroll
      for (int r = 0; r < 4; ++r) {
        float v = acc[i][j][r];
        size_t off = (size_t)(gm + r) * ldc + gn;
        if (epi == 0) {
          ((float*)Cout)[off] = v;
        } else if (epi == 1) {
          ((unsigned short*)Cout)[off] = f2b(v);
        } else if (epi == 2) {
          float x = v + bias[gn];
          float u = 0.7978845608028654f * (x + 0.044715f * x * x * x);
          ((unsigned short*)Cout)[off] = f2b(0.5f * x * (1.f + tanhf(u)));
        } else if (epi == 3) {
          ((float*)Cout)[off] = v + res[off];
        } else if (epi == 4) {
          ((float*)Cout)[off] = v + bias[gn] + res[off];
        } else if (epi == 5) {
          float x = v + bias[gn];
          ((float*)Cout)[off] = (x > 20.f) ? x : log1pf(__expf(x));
        } else if (epi == 6) {
          pdst[off] = v;
        } else {
          pdstb[off] = f2b(v);
        }
      }
    }
  }
}

// in-place reduce of 2 bf16 split-K partials: p[i] = p[i] + p[i+TN]  (bf16)
__global__ __launch_bounds__(256) void reduce2b_k(unsigned short* __restrict__ p) {
  int i = blockIdx.x * 256 + threadIdx.x;  // x4 elems, over T*4096/4
  const size_t TN = (size_t)T_TOK * 4096;
  ushort4 a = ((ushort4*)p)[i];
  ushort4 b = *(const ushort4*)(p + TN + (size_t)i * 4);
  ushort4 o;
  o.x = f2b(b2f(a.x) + b2f(b.x));
  o.y = f2b(b2f(a.y) + b2f(b.y));
  o.z = f2b(b2f(a.z) + b2f(b.z));
  o.w = f2b(b2f(a.w) + b2f(b.w));
  ((ushort4*)p)[i] = o;
}

// in-place reduce of 2 bf16 partials + bias + tanh-gelu (ffn1 epilogue)
__global__ __launch_bounds__(256) void reduce2g_k(unsigned short* __restrict__ p,
                                                  const float* __restrict__ bias) {
  int i = blockIdx.x * 256 + threadIdx.x;
  const size_t TN = (size_t)T_TOK * 4096;
  int gn = (i * 4) & 4095;
  float4 bi = *(const float4*)(bias + gn);
  ushort4 a = ((ushort4*)p)[i];
  ushort4 b = *(const ushort4*)(p + TN + (size_t)i * 4);
  float x0 = b2f(a.x) + b2f(b.x) + bi.x;
  float x1 = b2f(a.y) + b2f(b.y) + bi.y;
  float x2 = b2f(a.z) + b2f(b.z) + bi.z;
  float x3 = b2f(a.w) + b2f(b.w) + bi.w;
  ushort4 o;
  float u;
  u = 0.7978845608028654f * (x0 + 0.044715f * x0 * x0 * x0);
  o.x = f2b(0.5f * x0 * (1.f + tanhf(u)));
  u = 0.7978845608028654f * (x1 + 0.044715f * x1 * x1 * x1);
  o.y = f2b(0.5f * x1 * (1.f + tanhf(u)));
  u = 0.7978845608028654f * (x2 + 0.044715f * x2 * x2 * x2);
  o.z = f2b(0.5f * x2 * (1.f + tanhf(u)));
  u = 0.7978845608028654f * (x3 + 0.044715f * x3 * x3 * x3);
  o.w = f2b(0.5f * x3 * (1.f + tanhf(u)));
  ((ushort4*)p)[i] = o;
}

// reduce 4 split-K partials (+bias +res) -> out fp32.  N must be 1024 (=DM).
__global__ __launch_bounds__(256) void reduce4_k(const float* __restrict__ p0,
                                                 const float* __restrict__ p1,
                                                 float* __restrict__ out,
                                                 const float* __restrict__ bias,
                                                 const float* __restrict__ res) {
  int i = blockIdx.x * 256 + threadIdx.x;  // < T_TOK*DM
  const size_t TN = (size_t)T_TOK * DM;
  float s = p0[i] + p0[i + TN] + p1[i] + p1[i + TN];
  if (bias) s += bias[i & (DM - 1)];
  if (res) s += res[i];
  out[i] = s;
}

// fused: reduce 4 out_proj partials + residual -> xres (fp32) ; LN2 -> bf16
// one block per token; 256 threads x 4 elems = 1024 dims
__global__ __launch_bounds__(256) void reduce4ln_k(
    const float* __restrict__ p0, const float* __restrict__ p1,
    float* __restrict__ xres, const float* __restrict__ w,
    const float* __restrict__ bb, unsigned short* __restrict__ uout) {
  int t = blockIdx.x, tid = threadIdx.x;
  int wv = tid >> 6, ln = tid & 63;
  __shared__ float sm[2][4];
  size_t base = (size_t)t * DM + tid * 4;
  const size_t TN = (size_t)T_TOK * DM;
  float4 a = *(const float4*)(p0 + base);
  float4 b4 = *(const float4*)(p0 + base + TN);
  float4 c = *(const float4*)(p1 + base);
  float4 d4 = *(const float4*)(p1 + base + TN);
  float4 r = *(const float4*)(xres + base);
  float v0 = a.x + b4.x + c.x + d4.x + r.x;
  float v1 = a.y + b4.y + c.y + d4.y + r.y;
  float v2 = a.z + b4.z + c.z + d4.z + r.z;
  float v3 = a.w + b4.w + c.w + d4.w + r.w;
  *(float4*)(xres + base) = make_float4(v0, v1, v2, v3);
  float s = v0 + v1 + v2 + v3;
  for (int o = 32; o > 0; o >>= 1) s += __shfl_down(s, o, 64);
  if (ln == 0) sm[0][wv] = s;
  __syncthreads();
  float mu = (sm[0][0] + sm[0][1] + sm[0][2] + sm[0][3]) * (1.0f / DM);
  float d0 = v0 - mu, d1 = v1 - mu, d2 = v2 - mu, d3 = v3 - mu;
  float sq = d0 * d0 + d1 * d1 + d2 * d2 + d3 * d3;
  for (int o = 32; o > 0; o >>= 1) sq += __shfl_down(sq, o, 64);
  if (ln == 0) sm[1][wv] = sq;
  __syncthreads();
  float rs = rsqrtf((sm[1][0] + sm[1][1] + sm[1][2] + sm[1][3]) * (1.0f / DM) + 1e-5f);
  float4 w4 = *(const float4*)(w + tid * 4);
  float4 bb4 = *(const float4*)(bb + tid * 4);
  ushort4 o;
  o.x = f2b(d0 * rs * w4.x + bb4.x);
  o.y = f2b(d1 * rs * w4.y + bb4.y);
  o.z = f2b(d2 * rs * w4.z + bb4.z);
  o.w = f2b(d3 * rs * w4.w + bb4.w);
  *(ushort4*)(uout + (size_t)t * DM + tid * 4) = o;
}

// ---------------------------------------------------------------------------
// x_proj split-K bf16 MFMA: part[ks][m][n] = sum_{k chunk} xcb[m,k]*W[n,k]
// ---------------------------------------------------------------------------
__global__ __launch_bounds__(256) void xproj_k(
    const unsigned short* __restrict__ xcb, const unsigned short* __restrict__ wpb,
    float* __restrict__ part) {
  __shared__ __align__(16) unsigned short As[4][64][8];
  __shared__ __align__(16) unsigned short Bs[32][96][8];
  int tid = threadIdx.x;
  int lane = tid & 63, wv = tid >> 6;
  int ml = lane & 15, kq = lane >> 4;
  int m0 = blockIdx.x * 64;
  int ks = blockIdx.y;
  int kbase = ks * 256;
  for (int e = tid; e < 3072; e += 256) {
    int row = e >> 5, slab = e & 31;
    *(int4*)&Bs[slab][row][0] = *(const int4*)(wpb + (size_t)row * DI + kbase + slab * 8);
  }
  floatx4 acc[6] = {};
  for (int s = 0; s < 8; ++s) {
    async16(&As[wv][0][0],
            xcb + (size_t)(m0 + lane) * DI + kbase + s * 32 + wv * 8);
    __syncthreads();
    short8 af = *(const short8*)&As[kq][wv * 16 + ml][0];
#pragma unroll
    for (int j = 0; j < 6; ++j) {
      short8 bf = *(const short8*)&Bs[s * 4 + kq][j * 16 + ml][0];
      acc[j] = __builtin_amdgcn_mfma_f32_16x16x32_bf16(af, bf, acc[j], 0, 0, 0);
    }
    __syncthreads();
  }
  float* dst = part + (size_t)ks * (T_TOK * XD);
#pragma unroll
  for (int j = 0; j < 6; ++j) {
    int gn = j * 16 + ml;
    int gm = m0 + wv * 16 + kq * 4;
#pragma unroll
    for (int r = 0; r < 4; ++r) dst[(size_t)(gm + r) * XD + gn] = acc[j][r];
  }
}

// reduce x_proj partials -> x_dbl fp32 [T,96]; dt part as bf16 [T,64]
__global__ __launch_bounds__(256) void xreduce_k(const float* __restrict__ part,
                                                 float* __restrict__ xdbl,
                                                 unsigned short* __restrict__ dtb) {
  int i = blockIdx.x * 256 + threadIdx.x;  // < T_TOK*XD
  float s = 0.f;
#pragma unroll
  for (int ks = 0; ks < SPLITK; ++ks) s += part[(size_t)ks * (T_TOK * XD) + i];
  xdbl[i] = s;
  int t = i / XD, c = i - t * XD;
  if (c < DTR) dtb[(size_t)t * DTR + c] = f2b(s);
}

// ---------------------------------------------------------------------------
// Causal depthwise conv (k=4) + bias + SiLU. Reads bf16 x-half of xz
// (row stride 2*DI). Emits fp32 (scan) + bf16 (x_proj).
// ---------------------------------------------------------------------------
__global__ __launch_bounds__(256) void conv_silu_k(
    const unsigned short* __restrict__ xzb, const float* __restrict__ cw,
    const float* __restrict__ cb, float* __restrict__ xc,
    unsigned short* __restrict__ xcb) {
  int idx = blockIdx.x * 256 + threadIdx.x;  // over T_TOK*DI
  int d = idx & (DI - 1);
  int t = idx >> 11;
  int l = t & (SEQ - 1);
  const unsigned short* base = xzb + (size_t)t * (2 * DI) + d;
  float4 w4 = *(const float4*)(cw + d * 4);
  float s = cb[d] + w4.w * b2f(base[0]);
  if (l >= 1) s = fmaf(w4.z, b2f(base[-(2 * DI)]), s);
  if (l >= 2) s = fmaf(w4.y, b2f(base[-2 * (2 * DI)]), s);
  if (l >= 3) s = fmaf(w4.x, b2f(base[-3 * (2 * DI)]), s);
  float y = s / (1.f + __expf(-s));  // silu
  xc[(size_t)t * DI + d] = y;
  xcb[(size_t)t * DI + d] = f2b(y);
}

// ---------------------------------------------------------------------------
// Chunked selective scan, 4 states per thread.
// idx: [1:0]=ng (state group), [12:2]=d, [16:13]=chunk, [17]=b
// ---------------------------------------------------------------------------
__global__ __launch_bounds__(256) void scan1_k(
    const float* __restrict__ delta, const float* __restrict__ xc,
    const float* __restrict__ xdbl, const float* __restrict__ A_log,
    float* __restrict__ hend, float* __restrict__ aprod) {
  int idx = blockIdx.x * 256 + threadIdx.x;
  int ng = idx & 3;
  int d = (idx >> 2) & (DI - 1);
  int c = (idx >> 13) & (NCHK - 1);
  int b = idx >> 17;
  const float* ap_ = A_log + d * NST + ng * 4;
  float a0 = -__expf(ap_[0]), a1 = -__expf(ap_[1]);
  float a2 = -__expf(ap_[2]), a3 = -__expf(ap_[3]);
  float h0 = 0.f, h1 = 0.f, h2 = 0.f, h3 = 0.f;
  float q0 = 1.f, q1 = 1.f, q2 = 1.f, q3 = 1.f;
  int t = b * SEQ + c * CHK;
  const float* dp = delta + (size_t)t * DI + d;
  const float* xp = xc + (size_t)t * DI + d;
  const float* bp = xdbl + (size_t)t * XD + DTR + ng * 4;
  for (int l = 0; l < CHK; ++l) {
    float dv = *dp;
    float xv = *xp;
    float4 B4 = *(const float4*)bp;
    float dx = dv * xv;
    float e0 = __expf(dv * a0), e1 = __expf(dv * a1);
    float e2 = __expf(dv * a2), e3 = __expf(dv * a3);
    q0 *= e0; q1 *= e1; q2 *= e2; q3 *= e3;
    h0 = fmaf(e0, h0, dx * B4.x);
    h1 = fmaf(e1, h1, dx * B4.y);
    h2 = fmaf(e2, h2, dx * B4.z);
    h3 = fmaf(e3, h3, dx * B4.w);
    dp += DI; xp += DI; bp += XD;
  }
  size_t o = ((size_t)(b * NCHK + c) * DI + d) * NST + ng * 4;
  *(float4*)&hend[o] = make_float4(h0, h1, h2, h3);
  *(float4*)&aprod[o] = make_float4(q0, q1, q2, q3);
}

__global__ __launch_bounds__(256) void scan2_k(
    const float* __restrict__ delta, const float* __restrict__ xc,
    const float* __restrict__ xdbl, const unsigned short* __restrict__ xzb,
    const float* __restrict__ A_log, const float* __restrict__ Dsk,
    const float* __restrict__ hend, const float* __restrict__ aprod,
    unsigned short* __restrict__ y) {
  int idx = blockIdx.x * 256 + threadIdx.x;
  int ng = idx & 3;
  int d = (idx >> 2) & (DI - 1);
  int c = (idx >> 13) & (NCHK - 1);
  int b = idx >> 17;
  const float* ap_ = A_log + d * NST + ng * 4;
  float a0 = -__expf(ap_[0]), a1 = -__expf(ap_[1]);
  float a2 = -__expf(ap_[2]), a3 = -__expf(ap_[3]);
  float dskip = Dsk[d];
  float h0 = 0.f, h1 = 0.f, h2 = 0.f, h3 = 0.f;
  for (int pc = 0; pc < c; ++pc) {
    size_t o = ((size_t)(b * NCHK + pc) * DI + d) * NST + ng * 4;
    float4 ap4 = *(const float4*)&aprod[o];
    float4 he4 = *(const float4*)&hend[o];
    h0 = fmaf(ap4.x, h0, he4.x);
    h1 = fmaf(ap4.y, h1, he4.y);
    h2 = fmaf(ap4.z, h2, he4.z);
    h3 = fmaf(ap4.w, h3, he4.w);
  }
  int t = b * SEQ + c * CHK;
  const float* dp = delta + (size_t)t * DI + d;
  const float* xp = xc + (size_t)t * DI + d;
  const float* bp = xdbl + (size_t)t * XD + DTR + ng * 4;
  const float* cp = xdbl + (size_t)t * XD + DTR + NST + ng * 4;
  const unsigned short* zp = xzb + (size_t)t * (2 * DI) + DI + d;
  unsigned short* yp = y + (size_t)t * DI + d;
  for (int l = 0; l < CHK; ++l) {
    float dv = *dp;
    float xv = *xp;
    float4 B4 = *(const float4*)bp;
    float4 C4 = *(const float4*)cp;
    float dx = dv * xv;
    float e0 = __expf(dv * a0), e1 = __expf(dv * a1);
    float e2 = __expf(dv * a2), e3 = __expf(dv * a3);
    h0 = fmaf(e0, h0, dx * B4.x);
    h1 = fmaf(e1, h1, dx * B4.y);
    h2 = fmaf(e2, h2, dx * B4.z);
    h3 = fmaf(e3, h3, dx * B4.w);
    float contrib = h0 * C4.x + h1 * C4.y + h2 * C4.z + h3 * C4.w;
    contrib += __shfl_xor(contrib, 1);
    contrib += __shfl_xor(contrib, 2);
    if (ng == 0) {
      float zv = b2f(*zp);
      float sig = zv / (1.f + __expf(-zv));
      *yp = f2b((contrib + xv * dskip) * sig);
    }
    dp += DI; xp += DI; bp += XD; cp += XD; zp += 2 * DI; yp += DI;
  }
}

// ---------------------------------------------------------------------------
extern "C" void kernel_launch(void* const* d_in, const int* in_sizes, int n_in,
                              void* d_out, int out_size, void* d_ws,
                              size_t ws_size, hipStream_t stream) {
  const float* x_in      = (const float*)d_in[0];
  const float* ln0_w     = (const float*)d_in[1];
  const float* ln0_b     = (const float*)d_in[2];
  const float* ln1_w     = (const float*)d_in[3];
  const float* ln1_b     = (const float*)d_in[4];
  const float* ln2_w     = (const float*)d_in[5];
  const float* ln2_b     = (const float*)d_in[6];
  const float* in_proj_w = (const float*)d_in[7];
  const float* conv_w    = (const float*)d_in[8];
  const float* conv_b    = (const float*)d_in[9];
  const float* x_proj_w  = (const float*)d_in[10];
  const float* dt_proj_w = (const float*)d_in[11];
  const float* dt_proj_b = (const float*)d_in[12];
  const float* A_log     = (const float*)d_in[13];
  const float* D_skip    = (const float*)d_in[14];
  const float* out_proj_w= (const float*)d_in[15];
  const float* ffn_w1    = (const float*)d_in[16];
  const float* ffn_b1    = (const float*)d_in[17];
  const float* ffn_w2    = (const float*)d_in[18];
  const float* ffn_b2    = (const float*)d_in[19];
  float* out = (float*)d_out;

  // Workspace layout (floats), liveness-aliased; total 20.12M floats = 80.5 MB
  float* ws    = (float*)d_ws;
  float* xws   = ws;                     // [T,DM] fp32 residual          2.097M
  float* big   = xws + 2097152;          // 2x bf16 partials / xzb / hbf  4.194M
  float* r2    = big + 4194304;          // ybf bf16 [T,DI]               2.097M
  float* xcws  = r2 + 2097152;           // xc fp32 / split-K partials    4.194M
  float* xdbl  = xcws + 4194304;         // [T,96] fp32                   0.197M
  float* dws   = xdbl + 196608;          // xcb bf16 / delta fp32 / parts 4.194M
  float* ubf_f = dws + 4194304;          // [T,DM] bf16 LN out            1.049M
  float* wbf_f = ubf_f + 1048576;        // staging region                2.097M
  // aliases (timeline-checked):
  unsigned short* xzb  = (unsigned short*)big;   // in_proj out (reduced in place)
  unsigned short* hbf  = (unsigned short*)big;   // ffn1 out (reduced in place)
  unsigned short* ybf  = (unsigned short*)r2;    // scan2 -> out_proj
  unsigned short* ubf  = (unsigned short*)ubf_f;
  unsigned short* xcb  = (unsigned short*)dws;   // conv bf16, dies before dt_proj
  unsigned short* wbf  = (unsigned short*)wbf_f;
  float* part  = wbf_f;                          // xproj partials [8][T,96] 1.573M
  unsigned short* wpb = (unsigned short*)(wbf_f + 1572864);  // x_proj_w bf16
  unsigned short* dtb = (unsigned short*)(wbf_f + 1671168);  // dt bf16 [T,64]
  unsigned short* dwb = (unsigned short*)(wbf_f + 1736704);  // dt_proj_w bf16
  // scan summaries overwrite the whole staging region after dt_proj:
  float* hend  = wbf_f;                  // [1048576] = B*NCHK*DI*NST
  float* aprod = wbf_f + 1048576;        // [1048576]

  // 1: convert in_proj_w -> bf16 (4096x1024)
  f2b_k<<<(4096 * 1024) / 1024, 256, 0, stream>>>(in_proj_w, wbf);
  // 2: fused LN0+LN1 -> xws fp32, ubf bf16
  ln01_k<<<T_TOK, 256, 0, stream>>>(x_in, ln0_w, ln0_b, ln1_w, ln1_b, xws, ubf);
  // 3: in_proj split-K x2 (1024 blocks), bf16 partials into big; reduce in place
  {
    dim3 g((2 * DI) / 128, T_TOK / 128, 2);
    gemm_bf16<<<g, 256, 0, stream>>>(ubf, DM, wbf, DM, nullptr, 2 * DI, DM / 2, 8,
                                     nullptr, nullptr, big, nullptr);
    reduce2b_k<<<(T_TOK * 4096) / 1024, 256, 0, stream>>>(xzb);
  }
  // 4: causal conv + silu (bf16 in) -> xc fp32 + xcb bf16
  conv_silu_k<<<(T_TOK * DI) / 256, 256, 0, stream>>>(xzb, conv_w, conv_b, xcws, xcb);
  // 5: x_proj + dt_proj weights -> bf16 (one dispatch)
  f2b2_k<<<(XD * DI + DI * DTR) / 1024, 256, 0, stream>>>(
      x_proj_w, wpb, (XD * DI) / 4, dt_proj_w, dwb);
  // 6: x_proj split-K MFMA + reduce -> xdbl fp32, dtb bf16
  {
    dim3 g(T_TOK / 64, SPLITK);
    xproj_k<<<g, 256, 0, stream>>>(xcb, wpb, part);
    xreduce_k<<<(T_TOK * XD) / 256, 256, 0, stream>>>(part, xdbl, dtb);
  }
  // 7: dt_proj + softplus (bf16 MFMA) -> delta fp32
  {
    dim3 g(DI / 128, T_TOK / 128, 1);
    gemm_bf16<<<g, 256, 0, stream>>>(dtb, DTR, dwb, DTR, dws, DI, DTR, 5,
                                     dt_proj_b, nullptr, nullptr, nullptr);
  }
  // 8-9: chunked scan, 4 states/thread (summaries alias dead staging region)
  {
    int nthreads = 2 * NCHK * DI * 4;  // 262144
    scan1_k<<<nthreads / 256, 256, 0, stream>>>(dws, xcws, xdbl, A_log,
                                                hend, aprod);
    scan2_k<<<nthreads / 256, 256, 0, stream>>>(dws, xcws, xdbl, xzb,
                                                A_log, D_skip, hend, aprod, ybf);
  }
  // 10: out_proj split-K x4 + fused reduce+residual+LN2 -> xws, ubf
  f2b_k<<<(DM * DI) / 1024, 256, 0, stream>>>(out_proj_w, wbf);
  {
    dim3 g(DM / 128, T_TOK / 128, 4);
    gemm_bf16<<<g, 256, 0, stream>>>(ybf, DI, wbf, DI, nullptr, DM, DI / 4, 6,
                                     nullptr, nullptr, xcws, dws);
    reduce4ln_k<<<T_TOK, 256, 0, stream>>>(xcws, dws, xws, ln2_w, ln2_b, ubf);
  }
  // 11: ffn1 split-K x2 (1024 blocks), bf16 partials into big; reduce+gelu
  f2b_k<<<(FFN * DM) / 1024, 256, 0, stream>>>(ffn_w1, wbf);
  {
    dim3 g(FFN / 128, T_TOK / 128, 2);
    gemm_bf16<<<g, 256, 0, stream>>>(ubf, DM, wbf, DM, nullptr, FFN, DM / 2, 8,
                                     nullptr, nullptr, big, nullptr);
    reduce2g_k<<<(T_TOK * FFN) / 1024, 256, 0, stream>>>(hbf, ffn_b1);
  }
  // 12: ffn2 split-K x4 + reduce(+bias+res) -> d_out
  f2b_k<<<(DM * FFN) / 1024, 256, 0, stream>>>(ffn_w2, wbf);
  {
    dim3 g(DM / 128, T_TOK / 128, 4);
    gemm_bf16<<<g, 256, 0, stream>>>(hbf, FFN, wbf, FFN, nullptr, DM, FFN / 4, 6,
                                     nullptr, nullptr, dws, xcws);
    reduce4_k<<<(T_TOK * DM) / 256, 256, 0, stream>>>(dws, xcws, out, ffn_b2, xws);
  }
}

// Round 9
// 545.108 us; speedup vs baseline: 1.0930x; 1.0930x over previous
//
#include <hip/hip_runtime.h>
#include <math.h>

// Problem constants (match reference)
#define T_TOK 2048   // B*L
#define SEQ   1024   // L
#define DM    1024   // d_model
#define DI    2048   // d_inner
#define FFN   4096
#define NST   16     // d_state
#define DTR   64     // dt_rank
#define XD    96     // dt_rank + 2*d_state
#define CHK   64     // scan chunk length
#define NCHK  16     // chunks per sequence
#define SPLITK 8     // x_proj K-splits (K chunk = 256)

typedef __attribute__((ext_vector_type(8))) short short8;
typedef __attribute__((ext_vector_type(4))) float floatx4;

__device__ __forceinline__ unsigned short f2b(float f) {
  unsigned u = __float_as_uint(f);
  unsigned r = (u + 0x7fff + ((u >> 16) & 1)) >> 16;  // RNE
  return (unsigned short)r;
}
__device__ __forceinline__ float b2f(unsigned short s) {
  return __uint_as_float(((unsigned)s) << 16);
}

// async global->LDS, 16 B per lane. lds must be the wave-uniform base
// (lane 0's destination); HW adds lane*16.
typedef const __attribute__((address_space(1))) unsigned int g_uint;
typedef __attribute__((address_space(3))) unsigned int l_uint;
__device__ __forceinline__ void async16(void* lds, const void* g) {
  __builtin_amdgcn_global_load_lds((g_uint*)(size_t)g,
                                   (l_uint*)(unsigned)(size_t)lds, 16, 0, 0);
}

// ---------------------------------------------------------------------------
// fp32 -> bf16 bulk convert (n multiple of 1024); 4 elems/thread
// ---------------------------------------------------------------------------
__global__ __launch_bounds__(256) void f2b_k(const float* __restrict__ in,
                                             unsigned short* __restrict__ out) {
  int i = blockIdx.x * 256 + threadIdx.x;
  float4 v = ((const float4*)in)[i];
  ushort4 o;
  o.x = f2b(v.x); o.y = f2b(v.y); o.z = f2b(v.z); o.w = f2b(v.w);
  ((ushort4*)out)[i] = o;
}

// two-tensor variant: converts a (na4 float4s) then b
__global__ __launch_bounds__(256) void f2b2_k(const float* __restrict__ a,
                                              unsigned short* __restrict__ oa,
                                              int na4,
                                              const float* __restrict__ b,
                                              unsigned short* __restrict__ ob) {
  int i = blockIdx.x * 256 + threadIdx.x;
  const float* in = (i < na4) ? a : b;
  unsigned short* out = (i < na4) ? oa : ob;
  int j = (i < na4) ? i : i - na4;
  float4 v = ((const float4*)in)[j];
  ushort4 o;
  o.x = f2b(v.x); o.y = f2b(v.y); o.z = f2b(v.z); o.w = f2b(v.w);
  ((ushort4*)out)[j] = o;
}

// ---------------------------------------------------------------------------
// Fused LN0+LN1: xout = LN0(x) fp32 (residual), uout = bf16(LN1(LN0(x)))
// ---------------------------------------------------------------------------
__global__ __launch_bounds__(256) void ln01_k(
    const float* __restrict__ in, const float* __restrict__ w0,
    const float* __restrict__ b0, const float* __restrict__ w1,
    const float* __restrict__ b1, float* __restrict__ xout,
    unsigned short* __restrict__ uout) {
  int t = blockIdx.x, tid = threadIdx.x;
  int wv = tid >> 6, ln = tid & 63;
  __shared__ float sm[4][4];
  float4 v = *(const float4*)(in + (size_t)t * DM + tid * 4);
  float s = v.x + v.y + v.z + v.w;
  for (int o = 32; o > 0; o >>= 1) s += __shfl_down(s, o, 64);
  if (ln == 0) sm[0][wv] = s;
  __syncthreads();
  float mu = (sm[0][0] + sm[0][1] + sm[0][2] + sm[0][3]) * (1.0f / DM);
  float d0 = v.x - mu, d1 = v.y - mu, d2 = v.z - mu, d3 = v.w - mu;
  float sq = d0 * d0 + d1 * d1 + d2 * d2 + d3 * d3;
  for (int o = 32; o > 0; o >>= 1) sq += __shfl_down(sq, o, 64);
  if (ln == 0) sm[1][wv] = sq;
  __syncthreads();
  float rs = rsqrtf((sm[1][0] + sm[1][1] + sm[1][2] + sm[1][3]) * (1.0f / DM) + 1e-5f);
  float4 w4 = *(const float4*)(w0 + tid * 4);
  float4 b4 = *(const float4*)(b0 + tid * 4);
  float r0 = d0 * rs * w4.x + b4.x, r1 = d1 * rs * w4.y + b4.y;
  float r2 = d2 * rs * w4.z + b4.z, r3 = d3 * rs * w4.w + b4.w;
  *(float4*)(xout + (size_t)t * DM + tid * 4) = make_float4(r0, r1, r2, r3);
  float s1 = r0 + r1 + r2 + r3;
  for (int o = 32; o > 0; o >>= 1) s1 += __shfl_down(s1, o, 64);
  if (ln == 0) sm[2][wv] = s1;
  __syncthreads();
  float mu1 = (sm[2][0] + sm[2][1] + sm[2][2] + sm[2][3]) * (1.0f / DM);
  float e0 = r0 - mu1, e1 = r1 - mu1, e2 = r2 - mu1, e3 = r3 - mu1;
  float sq1 = e0 * e0 + e1 * e1 + e2 * e2 + e3 * e3;
  for (int o = 32; o > 0; o >>= 1) sq1 += __shfl_down(sq1, o, 64);
  if (ln == 0) sm[3][wv] = sq1;
  __syncthreads();
  float rs1 = rsqrtf((sm[3][0] + sm[3][1] + sm[3][2] + sm[3][3]) * (1.0f / DM) + 1e-5f);
  float4 w14 = *(const float4*)(w1 + tid * 4);
  float4 b14 = *(const float4*)(b1 + tid * 4);
  ushort4 o;
  o.x = f2b(e0 * rs1 * w14.x + b14.x);
  o.y = f2b(e1 * rs1 * w14.y + b14.y);
  o.z = f2b(e2 * rs1 * w14.z + b14.z);
  o.w = f2b(e3 * rs1 * w14.w + b14.w);
  *(ushort4*)(uout + (size_t)t * DM + tid * 4) = o;
}

// ---------------------------------------------------------------------------
// bf16 MFMA GEMM (NT): C[m,n] = sum_k A[m,k]*W[n,k].  128x128 tile, 4 waves
// (2x2), 16x16x32 MFMA, BK=64 single-buffered global_load_lds staging
// (half the barrier drains of BK=32; R5's proven 2-barrier structure with
// 4 staging rounds instead of 2).  Split-K via blockIdx.z.
// epi: 0 fp32 | 1 bf16 | 2 gelu(acc+bias) bf16 | 3 acc+res fp32
//      4 acc+bias+res fp32 | 5 softplus(acc+bias) fp32 | 6 split-K fp32 partial
// partial base: z in {0,1} -> p0 + z*T*ldc ; z in {2,3} -> p1 + (z-2)*T*ldc
// ---------------------------------------------------------------------------
__global__ __launch_bounds__(256) void gemm_bf16(
    const unsigned short* __restrict__ A, int lda,
    const unsigned short* __restrict__ Bw, int ldb,
    void* __restrict__ Cout, int ldc, int Kc, int epi,
    const float* __restrict__ bias, const float* __restrict__ res,
    float* __restrict__ p0, float* __restrict__ p1) {
  __shared__ __align__(16) unsigned short As[8][128][8];  // [k-slab][row][8k]
  __shared__ __align__(16) unsigned short Bs[8][128][8];
  int tid = threadIdx.x;
  int lane = tid & 63, wv = tid >> 6;
  int wr = wv >> 1, wc = wv & 1;
  int m0 = blockIdx.y * 128, n0 = blockIdx.x * 128;
  int ml = lane & 15, kq = lane >> 4;
  int kstart = blockIdx.z * Kc;
  floatx4 acc[4][4] = {};
  for (int k0 = kstart; k0 < kstart + Kc; k0 += 64) {
    // stage A+B 128x64 each: 4 rounds x 256 threads x (1 A + 1 B) async16
#pragma unroll
    for (int r = 0; r < 4; ++r) {
      int c = tid + r * 256;
      int row = c & 127, slab = c >> 7;          // per-lane source
      int cw = wv * 64 + r * 256;
      int row0 = cw & 127, slab0 = cw >> 7;      // wave-uniform dest base
      async16(&As[slab0][row0][0], A + (size_t)(m0 + row) * lda + k0 + slab * 8);
      async16(&Bs[slab0][row0][0], Bw + (size_t)(n0 + row) * ldb + k0 + slab * 8);
    }
    __syncthreads();
#pragma unroll
    for (int ks = 0; ks < 2; ++ks) {
      short8 af[4], bfr[4];
#pragma unroll
      for (int i = 0; i < 4; ++i)
        af[i] = *(const short8*)&As[ks * 4 + kq][wr * 64 + i * 16 + ml][0];
#pragma unroll
      for (int j = 0; j < 4; ++j)
        bfr[j] = *(const short8*)&Bs[ks * 4 + kq][wc * 64 + j * 16 + ml][0];
#pragma unroll
      for (int i = 0; i < 4; ++i)
#pragma unroll
        for (int j = 0; j < 4; ++j)
          acc[i][j] =
              __builtin_amdgcn_mfma_f32_16x16x32_bf16(af[i], bfr[j], acc[i][j], 0, 0, 0);
    }
    __syncthreads();
  }
  float* pdst = nullptr;
  if (epi == 6) {
    pdst = (blockIdx.z & 2) ? p1 : p0;
    pdst += (size_t)(blockIdx.z & 1) * T_TOK * ldc;
  }
  // epilogue: D row = (lane>>4)*4 + r, col = lane&15
#pragma unroll
  for (int i = 0; i < 4; ++i) {
    int gm = m0 + wr * 64 + i * 16 + kq * 4;
#pragma unroll
    for (int j = 0; j < 4; ++j) {
      int gn = n0 + wc * 64 + j * 16 + ml;
#pragma unroll
      for (int r = 0; r < 4; ++r) {
        float v = acc[i][j][r];
        size_t off = (size_t)(gm + r) * ldc + gn;
        if (epi == 0) {
          ((float*)Cout)[off] = v;
        } else if (epi == 1) {
          ((unsigned short*)Cout)[off] = f2b(v);
        } else if (epi == 2) {
          float x = v + bias[gn];
          float u = 0.7978845608028654f * (x + 0.044715f * x * x * x);
          ((unsigned short*)Cout)[off] = f2b(0.5f * x * (1.f + tanhf(u)));
        } else if (epi == 3) {
          ((float*)Cout)[off] = v + res[off];
        } else if (epi == 4) {
          ((float*)Cout)[off] = v + bias[gn] + res[off];
        } else if (epi == 5) {
          float x = v + bias[gn];
          ((float*)Cout)[off] = (x > 20.f) ? x : log1pf(__expf(x));
        } else {
          pdst[off] = v;
        }
      }
    }
  }
}

// reduce 4 split-K partials (+bias +res) -> out fp32.  N must be 1024 (=DM).
__global__ __launch_bounds__(256) void reduce4_k(const float* __restrict__ p0,
                                                 const float* __restrict__ p1,
                                                 float* __restrict__ out,
                                                 const float* __restrict__ bias,
                                                 const float* __restrict__ res) {
  int i = blockIdx.x * 256 + threadIdx.x;  // < T_TOK*DM
  const size_t TN = (size_t)T_TOK * DM;
  float s = p0[i] + p0[i + TN] + p1[i] + p1[i + TN];
  if (bias) s += bias[i & (DM - 1)];
  if (res) s += res[i];
  out[i] = s;
}

// fused: reduce 4 out_proj partials + residual -> xres (fp32) ; LN2 -> bf16
__global__ __launch_bounds__(256) void reduce4ln_k(
    const float* __restrict__ p0, const float* __restrict__ p1,
    float* __restrict__ xres, const float* __restrict__ w,
    const float* __restrict__ bb, unsigned short* __restrict__ uout) {
  int t = blockIdx.x, tid = threadIdx.x;
  int wv = tid >> 6, ln = tid & 63;
  __shared__ float sm[2][4];
  size_t base = (size_t)t * DM + tid * 4;
  const size_t TN = (size_t)T_TOK * DM;
  float4 a = *(const float4*)(p0 + base);
  float4 b4 = *(const float4*)(p0 + base + TN);
  float4 c = *(const float4*)(p1 + base);
  float4 d4 = *(const float4*)(p1 + base + TN);
  float4 r = *(const float4*)(xres + base);
  float v0 = a.x + b4.x + c.x + d4.x + r.x;
  float v1 = a.y + b4.y + c.y + d4.y + r.y;
  float v2 = a.z + b4.z + c.z + d4.z + r.z;
  float v3 = a.w + b4.w + c.w + d4.w + r.w;
  *(float4*)(xres + base) = make_float4(v0, v1, v2, v3);
  float s = v0 + v1 + v2 + v3;
  for (int o = 32; o > 0; o >>= 1) s += __shfl_down(s, o, 64);
  if (ln == 0) sm[0][wv] = s;
  __syncthreads();
  float mu = (sm[0][0] + sm[0][1] + sm[0][2] + sm[0][3]) * (1.0f / DM);
  float d0 = v0 - mu, d1 = v1 - mu, d2 = v2 - mu, d3 = v3 - mu;
  float sq = d0 * d0 + d1 * d1 + d2 * d2 + d3 * d3;
  for (int o = 32; o > 0; o >>= 1) sq += __shfl_down(sq, o, 64);
  if (ln == 0) sm[1][wv] = sq;
  __syncthreads();
  float rs = rsqrtf((sm[1][0] + sm[1][1] + sm[1][2] + sm[1][3]) * (1.0f / DM) + 1e-5f);
  float4 w4 = *(const float4*)(w + tid * 4);
  float4 bb4 = *(const float4*)(bb + tid * 4);
  ushort4 o;
  o.x = f2b(d0 * rs * w4.x + bb4.x);
  o.y = f2b(d1 * rs * w4.y + bb4.y);
  o.z = f2b(d2 * rs * w4.z + bb4.z);
  o.w = f2b(d3 * rs * w4.w + bb4.w);
  *(ushort4*)(uout + (size_t)t * DM + tid * 4) = o;
}

// ---------------------------------------------------------------------------
// x_proj split-K bf16 MFMA: part[ks][m][n] = sum_{k chunk} xcb[m,k]*W[n,k]
// ---------------------------------------------------------------------------
__global__ __launch_bounds__(256) void xproj_k(
    const unsigned short* __restrict__ xcb, const unsigned short* __restrict__ wpb,
    float* __restrict__ part) {
  __shared__ __align__(16) unsigned short As[4][64][8];
  __shared__ __align__(16) unsigned short Bs[32][96][8];
  int tid = threadIdx.x;
  int lane = tid & 63, wv = tid >> 6;
  int ml = lane & 15, kq = lane >> 4;
  int m0 = blockIdx.x * 64;
  int ks = blockIdx.y;
  int kbase = ks * 256;
  for (int e = tid; e < 3072; e += 256) {
    int row = e >> 5, slab = e & 31;
    *(int4*)&Bs[slab][row][0] = *(const int4*)(wpb + (size_t)row * DI + kbase + slab * 8);
  }
  floatx4 acc[6] = {};
  for (int s = 0; s < 8; ++s) {
    async16(&As[wv][0][0],
            xcb + (size_t)(m0 + lane) * DI + kbase + s * 32 + wv * 8);
    __syncthreads();
    short8 af = *(const short8*)&As[kq][wv * 16 + ml][0];
#pragma unroll
    for (int j = 0; j < 6; ++j) {
      short8 bf = *(const short8*)&Bs[s * 4 + kq][j * 16 + ml][0];
      acc[j] = __builtin_amdgcn_mfma_f32_16x16x32_bf16(af, bf, acc[j], 0, 0, 0);
    }
    __syncthreads();
  }
  float* dst = part + (size_t)ks * (T_TOK * XD);
#pragma unroll
  for (int j = 0; j < 6; ++j) {
    int gn = j * 16 + ml;
    int gm = m0 + wv * 16 + kq * 4;
#pragma unroll
    for (int r = 0; r < 4; ++r) dst[(size_t)(gm + r) * XD + gn] = acc[j][r];
  }
}

// reduce x_proj partials -> x_dbl fp32 [T,96]; dt part as bf16 [T,64]
__global__ __launch_bounds__(256) void xreduce_k(const float* __restrict__ part,
                                                 float* __restrict__ xdbl,
                                                 unsigned short* __restrict__ dtb) {
  int i = blockIdx.x * 256 + threadIdx.x;  // < T_TOK*XD
  float s = 0.f;
#pragma unroll
  for (int ks = 0; ks < SPLITK; ++ks) s += part[(size_t)ks * (T_TOK * XD) + i];
  xdbl[i] = s;
  int t = i / XD, c = i - t * XD;
  if (c < DTR) dtb[(size_t)t * DTR + c] = f2b(s);
}

// ---------------------------------------------------------------------------
// Causal depthwise conv (k=4) + bias + SiLU. Reads bf16 x-half of xz
// (row stride 2*DI). Emits fp32 (scan) + bf16 (x_proj).
// ---------------------------------------------------------------------------
__global__ __launch_bounds__(256) void conv_silu_k(
    const unsigned short* __restrict__ xzb, const float* __restrict__ cw,
    const float* __restrict__ cb, float* __restrict__ xc,
    unsigned short* __restrict__ xcb) {
  int idx = blockIdx.x * 256 + threadIdx.x;  // over T_TOK*DI
  int d = idx & (DI - 1);
  int t = idx >> 11;
  int l = t & (SEQ - 1);
  const unsigned short* base = xzb + (size_t)t * (2 * DI) + d;
  float4 w4 = *(const float4*)(cw + d * 4);
  float s = cb[d] + w4.w * b2f(base[0]);
  if (l >= 1) s = fmaf(w4.z, b2f(base[-(2 * DI)]), s);
  if (l >= 2) s = fmaf(w4.y, b2f(base[-2 * (2 * DI)]), s);
  if (l >= 3) s = fmaf(w4.x, b2f(base[-3 * (2 * DI)]), s);
  float y = s / (1.f + __expf(-s));  // silu
  xc[(size_t)t * DI + d] = y;
  xcb[(size_t)t * DI + d] = f2b(y);
}

// ---------------------------------------------------------------------------
// Chunked selective scan, 4 states per thread.
// idx: [1:0]=ng (state group), [12:2]=d, [16:13]=chunk, [17]=b
// ---------------------------------------------------------------------------
__global__ __launch_bounds__(256) void scan1_k(
    const float* __restrict__ delta, const float* __restrict__ xc,
    const float* __restrict__ xdbl, const float* __restrict__ A_log,
    float* __restrict__ hend, float* __restrict__ aprod) {
  int idx = blockIdx.x * 256 + threadIdx.x;
  int ng = idx & 3;
  int d = (idx >> 2) & (DI - 1);
  int c = (idx >> 13) & (NCHK - 1);
  int b = idx >> 17;
  const float* ap_ = A_log + d * NST + ng * 4;
  float a0 = -__expf(ap_[0]), a1 = -__expf(ap_[1]);
  float a2 = -__expf(ap_[2]), a3 = -__expf(ap_[3]);
  float h0 = 0.f, h1 = 0.f, h2 = 0.f, h3 = 0.f;
  float q0 = 1.f, q1 = 1.f, q2 = 1.f, q3 = 1.f;
  int t = b * SEQ + c * CHK;
  const float* dp = delta + (size_t)t * DI + d;
  const float* xp = xc + (size_t)t * DI + d;
  const float* bp = xdbl + (size_t)t * XD + DTR + ng * 4;
  for (int l = 0; l < CHK; ++l) {
    float dv = *dp;
    float xv = *xp;
    float4 B4 = *(const float4*)bp;
    float dx = dv * xv;
    float e0 = __expf(dv * a0), e1 = __expf(dv * a1);
    float e2 = __expf(dv * a2), e3 = __expf(dv * a3);
    q0 *= e0; q1 *= e1; q2 *= e2; q3 *= e3;
    h0 = fmaf(e0, h0, dx * B4.x);
    h1 = fmaf(e1, h1, dx * B4.y);
    h2 = fmaf(e2, h2, dx * B4.z);
    h3 = fmaf(e3, h3, dx * B4.w);
    dp += DI; xp += DI; bp += XD;
  }
  size_t o = ((size_t)(b * NCHK + c) * DI + d) * NST + ng * 4;
  *(float4*)&hend[o] = make_float4(h0, h1, h2, h3);
  *(float4*)&aprod[o] = make_float4(q0, q1, q2, q3);
}

__global__ __launch_bounds__(256) void scan2_k(
    const float* __restrict__ delta, const float* __restrict__ xc,
    const float* __restrict__ xdbl, const unsigned short* __restrict__ xzb,
    const float* __restrict__ A_log, const float* __restrict__ Dsk,
    const float* __restrict__ hend, const float* __restrict__ aprod,
    unsigned short* __restrict__ y) {
  int idx = blockIdx.x * 256 + threadIdx.x;
  int ng = idx & 3;
  int d = (idx >> 2) & (DI - 1);
  int c = (idx >> 13) & (NCHK - 1);
  int b = idx >> 17;
  const float* ap_ = A_log + d * NST + ng * 4;
  float a0 = -__expf(ap_[0]), a1 = -__expf(ap_[1]);
  float a2 = -__expf(ap_[2]), a3 = -__expf(ap_[3]);
  float dskip = Dsk[d];
  float h0 = 0.f, h1 = 0.f, h2 = 0.f, h3 = 0.f;
  for (int pc = 0; pc < c; ++pc) {
    size_t o = ((size_t)(b * NCHK + pc) * DI + d) * NST + ng * 4;
    float4 ap4 = *(const float4*)&aprod[o];
    float4 he4 = *(const float4*)&hend[o];
    h0 = fmaf(ap4.x, h0, he4.x);
    h1 = fmaf(ap4.y, h1, he4.y);
    h2 = fmaf(ap4.z, h2, he4.z);
    h3 = fmaf(ap4.w, h3, he4.w);
  }
  int t = b * SEQ + c * CHK;
  const float* dp = delta + (size_t)t * DI + d;
  const float* xp = xc + (size_t)t * DI + d;
  const float* bp = xdbl + (size_t)t * XD + DTR + ng * 4;
  const float* cp = xdbl + (size_t)t * XD + DTR + NST + ng * 4;
  const unsigned short* zp = xzb + (size_t)t * (2 * DI) + DI + d;
  unsigned short* yp = y + (size_t)t * DI + d;
  for (int l = 0; l < CHK; ++l) {
    float dv = *dp;
    float xv = *xp;
    float4 B4 = *(const float4*)bp;
    float4 C4 = *(const float4*)cp;
    float dx = dv * xv;
    float e0 = __expf(dv * a0), e1 = __expf(dv * a1);
    float e2 = __expf(dv * a2), e3 = __expf(dv * a3);
    h0 = fmaf(e0, h0, dx * B4.x);
    h1 = fmaf(e1, h1, dx * B4.y);
    h2 = fmaf(e2, h2, dx * B4.z);
    h3 = fmaf(e3, h3, dx * B4.w);
    float contrib = h0 * C4.x + h1 * C4.y + h2 * C4.z + h3 * C4.w;
    contrib += __shfl_xor(contrib, 1);
    contrib += __shfl_xor(contrib, 2);
    if (ng == 0) {
      float zv = b2f(*zp);
      float sig = zv / (1.f + __expf(-zv));
      *yp = f2b((contrib + xv * dskip) * sig);
    }
    dp += DI; xp += DI; bp += XD; cp += XD; zp += 2 * DI; yp += DI;
  }
}

// ---------------------------------------------------------------------------
extern "C" void kernel_launch(void* const* d_in, const int* in_sizes, int n_in,
                              void* d_out, int out_size, void* d_ws,
                              size_t ws_size, hipStream_t stream) {
  const float* x_in      = (const float*)d_in[0];
  const float* ln0_w     = (const float*)d_in[1];
  const float* ln0_b     = (const float*)d_in[2];
  const float* ln1_w     = (const float*)d_in[3];
  const float* ln1_b     = (const float*)d_in[4];
  const float* ln2_w     = (const float*)d_in[5];
  const float* ln2_b     = (const float*)d_in[6];
  const float* in_proj_w = (const float*)d_in[7];
  const float* conv_w    = (const float*)d_in[8];
  const float* conv_b    = (const float*)d_in[9];
  const float* x_proj_w  = (const float*)d_in[10];
  const float* dt_proj_w = (const float*)d_in[11];
  const float* dt_proj_b = (const float*)d_in[12];
  const float* A_log     = (const float*)d_in[13];
  const float* D_skip    = (const float*)d_in[14];
  const float* out_proj_w= (const float*)d_in[15];
  const float* ffn_w1    = (const float*)d_in[16];
  const float* ffn_b1    = (const float*)d_in[17];
  const float* ffn_w2    = (const float*)d_in[18];
  const float* ffn_b2    = (const float*)d_in[19];
  float* out = (float*)d_out;

  // Workspace layout (floats), liveness-aliased; total 20.12M floats = 80.5 MB
  float* ws    = (float*)d_ws;
  float* xws   = ws;                     // [T,DM] fp32 residual          2.097M
  float* big   = xws + 2097152;          // xzb bf16 [T,4096] / hbf bf16  4.194M
  float* r2    = big + 4194304;          // ybf bf16 [T,DI]               2.097M
  float* xcws  = r2 + 2097152;           // xc fp32 / split-K partials    4.194M
  float* xdbl  = xcws + 4194304;         // [T,96] fp32                   0.197M
  float* dws   = xdbl + 196608;          // xcb bf16 / delta fp32 / parts 4.194M
  float* ubf_f = dws + 4194304;          // [T,DM] bf16 LN out            1.049M
  float* wbf_f = ubf_f + 1048576;        // staging region                2.097M
  // aliases (timeline-checked):
  unsigned short* xzb  = (unsigned short*)big;   // in_proj out, dies after scan2
  unsigned short* hbf  = (unsigned short*)big;   // ffn1 -> ffn2 [T,FFN] bf16
  unsigned short* ybf  = (unsigned short*)r2;    // scan2 -> out_proj
  unsigned short* ubf  = (unsigned short*)ubf_f;
  unsigned short* xcb  = (unsigned short*)dws;   // conv bf16, dies before dt_proj
  unsigned short* wbf  = (unsigned short*)wbf_f;
  float* part  = wbf_f;                          // xproj partials [8][T,96] 1.573M
  unsigned short* wpb = (unsigned short*)(wbf_f + 1572864);  // x_proj_w bf16
  unsigned short* dtb = (unsigned short*)(wbf_f + 1671168);  // dt bf16 [T,64]
  unsigned short* dwb = (unsigned short*)(wbf_f + 1736704);  // dt_proj_w bf16
  // scan summaries overwrite the whole staging region after dt_proj:
  float* hend  = wbf_f;                  // [1048576] = B*NCHK*DI*NST
  float* aprod = wbf_f + 1048576;        // [1048576]

  // 1: convert in_proj_w -> bf16 (4096x1024)
  f2b_k<<<(4096 * 1024) / 1024, 256, 0, stream>>>(in_proj_w, wbf);
  // 2: fused LN0+LN1 -> xws fp32, ubf bf16
  ln01_k<<<T_TOK, 256, 0, stream>>>(x_in, ln0_w, ln0_b, ln1_w, ln1_b, xws, ubf);
  // 3: in_proj, single dispatch N=4096 -> xzb bf16 (512 blocks, BK=64)
  {
    dim3 g((2 * DI) / 128, T_TOK / 128, 1);
    gemm_bf16<<<g, 256, 0, stream>>>(ubf, DM, wbf, DM, xzb, 2 * DI, DM, 1,
                                     nullptr, nullptr, nullptr, nullptr);
  }
  // 4: causal conv + silu (bf16 in) -> xc fp32 + xcb bf16
  conv_silu_k<<<(T_TOK * DI) / 256, 256, 0, stream>>>(xzb, conv_w, conv_b, xcws, xcb);
  // 5: x_proj + dt_proj weights -> bf16 (one dispatch)
  f2b2_k<<<(XD * DI + DI * DTR) / 1024, 256, 0, stream>>>(
      x_proj_w, wpb, (XD * DI) / 4, dt_proj_w, dwb);
  // 6: x_proj split-K MFMA + reduce -> xdbl fp32, dtb bf16
  {
    dim3 g(T_TOK / 64, SPLITK);
    xproj_k<<<g, 256, 0, stream>>>(xcb, wpb, part);
    xreduce_k<<<(T_TOK * XD) / 256, 256, 0, stream>>>(part, xdbl, dtb);
  }
  // 7: dt_proj + softplus (bf16 MFMA, 1 iter of BK=64) -> delta fp32
  {
    dim3 g(DI / 128, T_TOK / 128, 1);
    gemm_bf16<<<g, 256, 0, stream>>>(dtb, DTR, dwb, DTR, dws, DI, DTR, 5,
                                     dt_proj_b, nullptr, nullptr, nullptr);
  }
  // 8-9: chunked scan, 4 states/thread (summaries alias dead staging region)
  {
    int nthreads = 2 * NCHK * DI * 4;  // 262144
    scan1_k<<<nthreads / 256, 256, 0, stream>>>(dws, xcws, xdbl, A_log,
                                                hend, aprod);
    scan2_k<<<nthreads / 256, 256, 0, stream>>>(dws, xcws, xdbl, xzb,
                                                A_log, D_skip, hend, aprod, ybf);
  }
  // 10: out_proj split-K x4 + fused reduce+residual+LN2 -> xws, ubf
  f2b_k<<<(DM * DI) / 1024, 256, 0, stream>>>(out_proj_w, wbf);
  {
    dim3 g(DM / 128, T_TOK / 128, 4);
    gemm_bf16<<<g, 256, 0, stream>>>(ybf, DI, wbf, DI, nullptr, DM, DI / 4, 6,
                                     nullptr, nullptr, xcws, dws);
    reduce4ln_k<<<T_TOK, 256, 0, stream>>>(xcws, dws, xws, ln2_w, ln2_b, ubf);
  }
  // 11: ffn1 + bias + gelu -> hbf bf16 (512 blocks, BK=64)
  f2b_k<<<(FFN * DM) / 1024, 256, 0, stream>>>(ffn_w1, wbf);
  {
    dim3 g(FFN / 128, T_TOK / 128, 1);
    gemm_bf16<<<g, 256, 0, stream>>>(ubf, DM, wbf, DM, hbf, FFN, DM, 2,
                                     ffn_b1, nullptr, nullptr, nullptr);
  }
  // 12: ffn2 split-K x4 + reduce(+bias+res) -> d_out
  f2b_k<<<(DM * FFN) / 1024, 256, 0, stream>>>(ffn_w2, wbf);
  {
    dim3 g(DM / 128, T_TOK / 128, 4);
    gemm_bf16<<<g, 256, 0, stream>>>(hbf, FFN, wbf, FFN, nullptr, DM, FFN / 4, 6,
                                     nullptr, nullptr, dws, xcws);
    reduce4_k<<<(T_TOK * DM) / 256, 256, 0, stream>>>(dws, xcws, out, ffn_b2, xws);
  }
}

// Round 10
// 500.194 us; speedup vs baseline: 1.1911x; 1.0898x over previous
//
#include <hip/hip_runtime.h>
#include <math.h>

// Problem constants (match reference)
#define T_TOK 2048   // B*L
#define SEQ   1024   // L
#define DM    1024   // d_model
#define DI    2048   // d_inner
#define FFN   4096
#define NST   16     // d_state
#define DTR   64     // dt_rank
#define XD    96     // dt_rank + 2*d_state
#define CHK   64     // scan chunk length
#define NCHK  16     // chunks per sequence
#define SPLITK 8     // x_proj K-splits (K chunk = 256)

typedef __attribute__((ext_vector_type(8))) short short8;
typedef __attribute__((ext_vector_type(4))) float floatx4;

__device__ __forceinline__ unsigned short f2b(float f) {
  unsigned u = __float_as_uint(f);
  unsigned r = (u + 0x7fff + ((u >> 16) & 1)) >> 16;  // RNE
  return (unsigned short)r;
}
__device__ __forceinline__ float b2f(unsigned short s) {
  return __uint_as_float(((unsigned)s) << 16);
}

// async global->LDS, 16 B per lane. lds must be the wave-uniform base
// (lane 0's destination); HW adds lane*16.
typedef const __attribute__((address_space(1))) unsigned int g_uint;
typedef __attribute__((address_space(3))) unsigned int l_uint;
__device__ __forceinline__ void async16(void* lds, const void* g) {
  __builtin_amdgcn_global_load_lds((g_uint*)(size_t)g,
                                   (l_uint*)(unsigned)(size_t)lds, 16, 0, 0);
}

// ---------------------------------------------------------------------------
// fp32 -> bf16 bulk convert (n multiple of 1024); 4 elems/thread
// ---------------------------------------------------------------------------
__global__ __launch_bounds__(256) void f2b_k(const float* __restrict__ in,
                                             unsigned short* __restrict__ out) {
  int i = blockIdx.x * 256 + threadIdx.x;
  float4 v = ((const float4*)in)[i];
  ushort4 o;
  o.x = f2b(v.x); o.y = f2b(v.y); o.z = f2b(v.z); o.w = f2b(v.w);
  ((ushort4*)out)[i] = o;
}

// two-tensor variant: converts a (na4 float4s) then b
__global__ __launch_bounds__(256) void f2b2_k(const float* __restrict__ a,
                                              unsigned short* __restrict__ oa,
                                              int na4,
                                              const float* __restrict__ b,
                                              unsigned short* __restrict__ ob) {
  int i = blockIdx.x * 256 + threadIdx.x;
  const float* in = (i < na4) ? a : b;
  unsigned short* out = (i < na4) ? oa : ob;
  int j = (i < na4) ? i : i - na4;
  float4 v = ((const float4*)in)[j];
  ushort4 o;
  o.x = f2b(v.x); o.y = f2b(v.y); o.z = f2b(v.z); o.w = f2b(v.w);
  ((ushort4*)out)[j] = o;
}

// ---------------------------------------------------------------------------
// Fused LN0+LN1: xout = LN0(x) fp32 (residual), uout = bf16(LN1(LN0(x)))
// ---------------------------------------------------------------------------
__global__ __launch_bounds__(256) void ln01_k(
    const float* __restrict__ in, const float* __restrict__ w0,
    const float* __restrict__ b0, const float* __restrict__ w1,
    const float* __restrict__ b1, float* __restrict__ xout,
    unsigned short* __restrict__ uout) {
  int t = blockIdx.x, tid = threadIdx.x;
  int wv = tid >> 6, ln = tid & 63;
  __shared__ float sm[4][4];
  float4 v = *(const float4*)(in + (size_t)t * DM + tid * 4);
  float s = v.x + v.y + v.z + v.w;
  for (int o = 32; o > 0; o >>= 1) s += __shfl_down(s, o, 64);
  if (ln == 0) sm[0][wv] = s;
  __syncthreads();
  float mu = (sm[0][0] + sm[0][1] + sm[0][2] + sm[0][3]) * (1.0f / DM);
  float d0 = v.x - mu, d1 = v.y - mu, d2 = v.z - mu, d3 = v.w - mu;
  float sq = d0 * d0 + d1 * d1 + d2 * d2 + d3 * d3;
  for (int o = 32; o > 0; o >>= 1) sq += __shfl_down(sq, o, 64);
  if (ln == 0) sm[1][wv] = sq;
  __syncthreads();
  float rs = rsqrtf((sm[1][0] + sm[1][1] + sm[1][2] + sm[1][3]) * (1.0f / DM) + 1e-5f);
  float4 w4 = *(const float4*)(w0 + tid * 4);
  float4 b4 = *(const float4*)(b0 + tid * 4);
  float r0 = d0 * rs * w4.x + b4.x, r1 = d1 * rs * w4.y + b4.y;
  float r2 = d2 * rs * w4.z + b4.z, r3 = d3 * rs * w4.w + b4.w;
  *(float4*)(xout + (size_t)t * DM + tid * 4) = make_float4(r0, r1, r2, r3);
  float s1 = r0 + r1 + r2 + r3;
  for (int o = 32; o > 0; o >>= 1) s1 += __shfl_down(s1, o, 64);
  if (ln == 0) sm[2][wv] = s1;
  __syncthreads();
  float mu1 = (sm[2][0] + sm[2][1] + sm[2][2] + sm[2][3]) * (1.0f / DM);
  float e0 = r0 - mu1, e1 = r1 - mu1, e2 = r2 - mu1, e3 = r3 - mu1;
  float sq1 = e0 * e0 + e1 * e1 + e2 * e2 + e3 * e3;
  for (int o = 32; o > 0; o >>= 1) sq1 += __shfl_down(sq1, o, 64);
  if (ln == 0) sm[3][wv] = sq1;
  __syncthreads();
  float rs1 = rsqrtf((sm[3][0] + sm[3][1] + sm[3][2] + sm[3][3]) * (1.0f / DM) + 1e-5f);
  float4 w14 = *(const float4*)(w1 + tid * 4);
  float4 b14 = *(const float4*)(b1 + tid * 4);
  ushort4 o;
  o.x = f2b(e0 * rs1 * w14.x + b14.x);
  o.y = f2b(e1 * rs1 * w14.y + b14.y);
  o.z = f2b(e2 * rs1 * w14.z + b14.z);
  o.w = f2b(e3 * rs1 * w14.w + b14.w);
  *(ushort4*)(uout + (size_t)t * DM + tid * 4) = o;
}

// ---------------------------------------------------------------------------
// 64x128-tile bf16 MFMA GEMM (NT), BK=64, single-buffered, 2 barriers/iter.
// Grid (N/128, M/64) -> 1024 blocks for M=2048,N=4096 (4 blocks/CU).
// 4 waves 2x2: wave = 32 rows x 64 cols; acc 2x4.  Proven multi-round
// async16 staging only.  epi: 1 bf16 | 2 gelu(acc+bias) bf16
// ---------------------------------------------------------------------------
__global__ __launch_bounds__(256) void gemm64_k(
    const unsigned short* __restrict__ A, int lda,
    const unsigned short* __restrict__ Bw, int ldb,
    unsigned short* __restrict__ Cout, int ldc, int K, int epi,
    const float* __restrict__ bias) {
  __shared__ __align__(16) unsigned short As[8][64][8];   // 8 KB
  __shared__ __align__(16) unsigned short Bs[8][128][8];  // 16 KB
  int tid = threadIdx.x;
  int lane = tid & 63, wv = tid >> 6;
  int wr = wv >> 1, wc = wv & 1;
  int m0 = blockIdx.y * 64, n0 = blockIdx.x * 128;
  int ml = lane & 15, kq = lane >> 4;
  floatx4 acc[2][4] = {};
  for (int k0 = 0; k0 < K; k0 += 64) {
    // A: 64 rows x 8 slabs = 512 chunks, 2 rounds
#pragma unroll
    for (int r = 0; r < 2; ++r) {
      int c = tid + r * 256;
      int row = c & 63, slab = c >> 6;           // per-lane source
      int cw = wv * 64 + r * 256;
      int row0 = cw & 63, slab0 = cw >> 6;       // wave-uniform dest base
      async16(&As[slab0][row0][0], A + (size_t)(m0 + row) * lda + k0 + slab * 8);
    }
    // B: 128 rows x 8 slabs = 1024 chunks, 4 rounds
#pragma unroll
    for (int r = 0; r < 4; ++r) {
      int c = tid + r * 256;
      int row = c & 127, slab = c >> 7;
      int cw = wv * 64 + r * 256;
      int row0 = cw & 127, slab0 = cw >> 7;
      async16(&Bs[slab0][row0][0], Bw + (size_t)(n0 + row) * ldb + k0 + slab * 8);
    }
    __syncthreads();
#pragma unroll
    for (int ks = 0; ks < 2; ++ks) {
      short8 af[2], bfr[4];
#pragma unroll
      for (int i = 0; i < 2; ++i)
        af[i] = *(const short8*)&As[ks * 4 + kq][wr * 32 + i * 16 + ml][0];
#pragma unroll
      for (int j = 0; j < 4; ++j)
        bfr[j] = *(const short8*)&Bs[ks * 4 + kq][wc * 64 + j * 16 + ml][0];
#pragma unroll
      for (int i = 0; i < 2; ++i)
#pragma unroll
        for (int j = 0; j < 4; ++j)
          acc[i][j] =
              __builtin_amdgcn_mfma_f32_16x16x32_bf16(af[i], bfr[j], acc[i][j], 0, 0, 0);
    }
    __syncthreads();
  }
  // epilogue: D row = (lane>>4)*4 + r, col = lane&15
#pragma unroll
  for (int i = 0; i < 2; ++i) {
    int gm = m0 + wr * 32 + i * 16 + kq * 4;
#pragma unroll
    for (int j = 0; j < 4; ++j) {
      int gn = n0 + wc * 64 + j * 16 + ml;
#pragma unroll
      for (int r = 0; r < 4; ++r) {
        float v = acc[i][j][r];
        size_t off = (size_t)(gm + r) * ldc + gn;
        if (epi == 1) {
          Cout[off] = f2b(v);
        } else {
          float x = v + bias[gn];
          float u = 0.7978845608028654f * (x + 0.044715f * x * x * x);
          Cout[off] = f2b(0.5f * x * (1.f + tanhf(u)));
        }
      }
    }
  }
}

// ---------------------------------------------------------------------------
// 128x128 bf16 MFMA GEMM (NT), BK=64 single-buffered (R9-proven).
// Split-K via blockIdx.z.
// epi: 5 softplus(acc+bias) fp32 | 8 split-K bf16 partial (layer z of p0)
// ---------------------------------------------------------------------------
__global__ __launch_bounds__(256) void gemm_bf16(
    const unsigned short* __restrict__ A, int lda,
    const unsigned short* __restrict__ Bw, int ldb,
    void* __restrict__ Cout, int ldc, int Kc, int epi,
    const float* __restrict__ bias, unsigned short* __restrict__ p0) {
  __shared__ __align__(16) unsigned short As[8][128][8];  // [k-slab][row][8k]
  __shared__ __align__(16) unsigned short Bs[8][128][8];
  int tid = threadIdx.x;
  int lane = tid & 63, wv = tid >> 6;
  int wr = wv >> 1, wc = wv & 1;
  int m0 = blockIdx.y * 128, n0 = blockIdx.x * 128;
  int ml = lane & 15, kq = lane >> 4;
  int kstart = blockIdx.z * Kc;
  floatx4 acc[4][4] = {};
  for (int k0 = kstart; k0 < kstart + Kc; k0 += 64) {
#pragma unroll
    for (int r = 0; r < 4; ++r) {
      int c = tid + r * 256;
      int row = c & 127, slab = c >> 7;          // per-lane source
      int cw = wv * 64 + r * 256;
      int row0 = cw & 127, slab0 = cw >> 7;      // wave-uniform dest base
      async16(&As[slab0][row0][0], A + (size_t)(m0 + row) * lda + k0 + slab * 8);
      async16(&Bs[slab0][row0][0], Bw + (size_t)(n0 + row) * ldb + k0 + slab * 8);
    }
    __syncthreads();
#pragma unroll
    for (int ks = 0; ks < 2; ++ks) {
      short8 af[4], bfr[4];
#pragma unroll
      for (int i = 0; i < 4; ++i)
        af[i] = *(const short8*)&As[ks * 4 + kq][wr * 64 + i * 16 + ml][0];
#pragma unroll
      for (int j = 0; j < 4; ++j)
        bfr[j] = *(const short8*)&Bs[ks * 4 + kq][wc * 64 + j * 16 + ml][0];
#pragma unroll
      for (int i = 0; i < 4; ++i)
#pragma unroll
        for (int j = 0; j < 4; ++j)
          acc[i][j] =
              __builtin_amdgcn_mfma_f32_16x16x32_bf16(af[i], bfr[j], acc[i][j], 0, 0, 0);
    }
    __syncthreads();
  }
  unsigned short* pdstb = nullptr;
  if (epi == 8) pdstb = p0 + (size_t)blockIdx.z * T_TOK * ldc;
  // epilogue: D row = (lane>>4)*4 + r, col = lane&15
#pragma unroll
  for (int i = 0; i < 4; ++i) {
    int gm = m0 + wr * 64 + i * 16 + kq * 4;
#pragma unroll
    for (int j = 0; j < 4; ++j) {
      int gn = n0 + wc * 64 + j * 16 + ml;
#pragma unroll
      for (int r = 0; r < 4; ++r) {
        float v = acc[i][j][r];
        size_t off = (size_t)(gm + r) * ldc + gn;
        if (epi == 5) {
          float x = v + bias[gn];
          ((float*)Cout)[off] = (x > 20.f) ? x : log1pf(__expf(x));
        } else {
          pdstb[off] = f2b(v);
        }
      }
    }
  }
}

// reduce 4 bf16 split-K partials (+bias +res) -> out fp32.  N = 1024 (=DM).
__global__ __launch_bounds__(256) void reduce4b_k(
    const unsigned short* __restrict__ p, float* __restrict__ out,
    const float* __restrict__ bias, const float* __restrict__ res) {
  int i = blockIdx.x * 256 + threadIdx.x;  // x4 elems
  const size_t TN = (size_t)T_TOK * DM;
  int gn = (i * 4) & (DM - 1);
  float4 bi = *(const float4*)(bias + gn);
  float v0 = bi.x, v1 = bi.y, v2 = bi.z, v3 = bi.w;
#pragma unroll
  for (int z = 0; z < 4; ++z) {
    ushort4 a = *(const ushort4*)(p + z * TN + (size_t)i * 4);
    v0 += b2f(a.x); v1 += b2f(a.y); v2 += b2f(a.z); v3 += b2f(a.w);
  }
  float4 r = *(const float4*)(res + (size_t)i * 4);
  *(float4*)(out + (size_t)i * 4) =
      make_float4(v0 + r.x, v1 + r.y, v2 + r.z, v3 + r.w);
}

// fused: reduce 4 bf16 out_proj partials + residual -> xres fp32 ; LN2 -> bf16
__global__ __launch_bounds__(256) void reduce4lnb_k(
    const unsigned short* __restrict__ p, float* __restrict__ xres,
    const float* __restrict__ w, const float* __restrict__ bb,
    unsigned short* __restrict__ uout) {
  int t = blockIdx.x, tid = threadIdx.x;
  int wv = tid >> 6, ln = tid & 63;
  __shared__ float sm[2][4];
  size_t base = (size_t)t * DM + tid * 4;
  const size_t TN = (size_t)T_TOK * DM;
  float4 r = *(const float4*)(xres + base);
  float v0 = r.x, v1 = r.y, v2 = r.z, v3 = r.w;
#pragma unroll
  for (int z = 0; z < 4; ++z) {
    ushort4 a = *(const ushort4*)(p + z * TN + base);
    v0 += b2f(a.x); v1 += b2f(a.y); v2 += b2f(a.z); v3 += b2f(a.w);
  }
  *(float4*)(xres + base) = make_float4(v0, v1, v2, v3);
  float s = v0 + v1 + v2 + v3;
  for (int o = 32; o > 0; o >>= 1) s += __shfl_down(s, o, 64);
  if (ln == 0) sm[0][wv] = s;
  __syncthreads();
  float mu = (sm[0][0] + sm[0][1] + sm[0][2] + sm[0][3]) * (1.0f / DM);
  float d0 = v0 - mu, d1 = v1 - mu, d2 = v2 - mu, d3 = v3 - mu;
  float sq = d0 * d0 + d1 * d1 + d2 * d2 + d3 * d3;
  for (int o = 32; o > 0; o >>= 1) sq += __shfl_down(sq, o, 64);
  if (ln == 0) sm[1][wv] = sq;
  __syncthreads();
  float rs = rsqrtf((sm[1][0] + sm[1][1] + sm[1][2] + sm[1][3]) * (1.0f / DM) + 1e-5f);
  float4 w4 = *(const float4*)(w + tid * 4);
  float4 bb4 = *(const float4*)(bb + tid * 4);
  ushort4 o;
  o.x = f2b(d0 * rs * w4.x + bb4.x);
  o.y = f2b(d1 * rs * w4.y + bb4.y);
  o.z = f2b(d2 * rs * w4.z + bb4.z);
  o.w = f2b(d3 * rs * w4.w + bb4.w);
  *(ushort4*)(uout + (size_t)t * DM + tid * 4) = o;
}

// ---------------------------------------------------------------------------
// x_proj split-K bf16 MFMA: part[ks][m][n] = sum_{k chunk} xcb[m,k]*W[n,k]
// ---------------------------------------------------------------------------
__global__ __launch_bounds__(256) void xproj_k(
    const unsigned short* __restrict__ xcb, const unsigned short* __restrict__ wpb,
    float* __restrict__ part) {
  __shared__ __align__(16) unsigned short As[4][64][8];
  __shared__ __align__(16) unsigned short Bs[32][96][8];
  int tid = threadIdx.x;
  int lane = tid & 63, wv = tid >> 6;
  int ml = lane & 15, kq = lane >> 4;
  int m0 = blockIdx.x * 64;
  int ks = blockIdx.y;
  int kbase = ks * 256;
  for (int e = tid; e < 3072; e += 256) {
    int row = e >> 5, slab = e & 31;
    *(int4*)&Bs[slab][row][0] = *(const int4*)(wpb + (size_t)row * DI + kbase + slab * 8);
  }
  floatx4 acc[6] = {};
  for (int s = 0; s < 8; ++s) {
    async16(&As[wv][0][0],
            xcb + (size_t)(m0 + lane) * DI + kbase + s * 32 + wv * 8);
    __syncthreads();
    short8 af = *(const short8*)&As[kq][wv * 16 + ml][0];
#pragma unroll
    for (int j = 0; j < 6; ++j) {
      short8 bf = *(const short8*)&Bs[s * 4 + kq][j * 16 + ml][0];
      acc[j] = __builtin_amdgcn_mfma_f32_16x16x32_bf16(af, bf, acc[j], 0, 0, 0);
    }
    __syncthreads();
  }
  float* dst = part + (size_t)ks * (T_TOK * XD);
#pragma unroll
  for (int j = 0; j < 6; ++j) {
    int gn = j * 16 + ml;
    int gm = m0 + wv * 16 + kq * 4;
#pragma unroll
    for (int r = 0; r < 4; ++r) dst[(size_t)(gm + r) * XD + gn] = acc[j][r];
  }
}

// reduce x_proj partials -> x_dbl fp32 [T,96]; dt part as bf16 [T,64]
__global__ __launch_bounds__(256) void xreduce_k(const float* __restrict__ part,
                                                 float* __restrict__ xdbl,
                                                 unsigned short* __restrict__ dtb) {
  int i = blockIdx.x * 256 + threadIdx.x;  // < T_TOK*XD
  float s = 0.f;
#pragma unroll
  for (int ks = 0; ks < SPLITK; ++ks) s += part[(size_t)ks * (T_TOK * XD) + i];
  xdbl[i] = s;
  int t = i / XD, c = i - t * XD;
  if (c < DTR) dtb[(size_t)t * DTR + c] = f2b(s);
}

// ---------------------------------------------------------------------------
// Causal depthwise conv (k=4) + bias + SiLU. Reads bf16 x-half of xz
// (row stride 2*DI). Emits fp32 (scan) + bf16 (x_proj).
// ---------------------------------------------------------------------------
__global__ __launch_bounds__(256) void conv_silu_k(
    const unsigned short* __restrict__ xzb, const float* __restrict__ cw,
    const float* __restrict__ cb, float* __restrict__ xc,
    unsigned short* __restrict__ xcb) {
  int idx = blockIdx.x * 256 + threadIdx.x;  // over T_TOK*DI
  int d = idx & (DI - 1);
  int t = idx >> 11;
  int l = t & (SEQ - 1);
  const unsigned short* base = xzb + (size_t)t * (2 * DI) + d;
  float4 w4 = *(const float4*)(cw + d * 4);
  float s = cb[d] + w4.w * b2f(base[0]);
  if (l >= 1) s = fmaf(w4.z, b2f(base[-(2 * DI)]), s);
  if (l >= 2) s = fmaf(w4.y, b2f(base[-2 * (2 * DI)]), s);
  if (l >= 3) s = fmaf(w4.x, b2f(base[-3 * (2 * DI)]), s);
  float y = s / (1.f + __expf(-s));  // silu
  xc[(size_t)t * DI + d] = y;
  xcb[(size_t)t * DI + d] = f2b(y);
}

// ---------------------------------------------------------------------------
// Chunked selective scan, 4 states per thread.
// idx: [1:0]=ng (state group), [12:2]=d, [16:13]=chunk, [17]=b
// ---------------------------------------------------------------------------
__global__ __launch_bounds__(256) void scan1_k(
    const float* __restrict__ delta, const float* __restrict__ xc,
    const float* __restrict__ xdbl, const float* __restrict__ A_log,
    float* __restrict__ hend, float* __restrict__ aprod) {
  int idx = blockIdx.x * 256 + threadIdx.x;
  int ng = idx & 3;
  int d = (idx >> 2) & (DI - 1);
  int c = (idx >> 13) & (NCHK - 1);
  int b = idx >> 17;
  const float* ap_ = A_log + d * NST + ng * 4;
  float a0 = -__expf(ap_[0]), a1 = -__expf(ap_[1]);
  float a2 = -__expf(ap_[2]), a3 = -__expf(ap_[3]);
  float h0 = 0.f, h1 = 0.f, h2 = 0.f, h3 = 0.f;
  float q0 = 1.f, q1 = 1.f, q2 = 1.f, q3 = 1.f;
  int t = b * SEQ + c * CHK;
  const float* dp = delta + (size_t)t * DI + d;
  const float* xp = xc + (size_t)t * DI + d;
  const float* bp = xdbl + (size_t)t * XD + DTR + ng * 4;
  for (int l = 0; l < CHK; ++l) {
    float dv = *dp;
    float xv = *xp;
    float4 B4 = *(const float4*)bp;
    float dx = dv * xv;
    float e0 = __expf(dv * a0), e1 = __expf(dv * a1);
    float e2 = __expf(dv * a2), e3 = __expf(dv * a3);
    q0 *= e0; q1 *= e1; q2 *= e2; q3 *= e3;
    h0 = fmaf(e0, h0, dx * B4.x);
    h1 = fmaf(e1, h1, dx * B4.y);
    h2 = fmaf(e2, h2, dx * B4.z);
    h3 = fmaf(e3, h3, dx * B4.w);
    dp += DI; xp += DI; bp += XD;
  }
  size_t o = ((size_t)(b * NCHK + c) * DI + d) * NST + ng * 4;
  *(float4*)&hend[o] = make_float4(h0, h1, h2, h3);
  *(float4*)&aprod[o] = make_float4(q0, q1, q2, q3);
}

__global__ __launch_bounds__(256) void scan2_k(
    const float* __restrict__ delta, const float* __restrict__ xc,
    const float* __restrict__ xdbl, const unsigned short* __restrict__ xzb,
    const float* __restrict__ A_log, const float* __restrict__ Dsk,
    const float* __restrict__ hend, const float* __restrict__ aprod,
    unsigned short* __restrict__ y) {
  int idx = blockIdx.x * 256 + threadIdx.x;
  int ng = idx & 3;
  int d = (idx >> 2) & (DI - 1);
  int c = (idx >> 13) & (NCHK - 1);
  int b = idx >> 17;
  const float* ap_ = A_log + d * NST + ng * 4;
  float a0 = -__expf(ap_[0]), a1 = -__expf(ap_[1]);
  float a2 = -__expf(ap_[2]), a3 = -__expf(ap_[3]);
  float dskip = Dsk[d];
  float h0 = 0.f, h1 = 0.f, h2 = 0.f, h3 = 0.f;
  for (int pc = 0; pc < c; ++pc) {
    size_t o = ((size_t)(b * NCHK + pc) * DI + d) * NST + ng * 4;
    float4 ap4 = *(const float4*)&aprod[o];
    float4 he4 = *(const float4*)&hend[o];
    h0 = fmaf(ap4.x, h0, he4.x);
    h1 = fmaf(ap4.y, h1, he4.y);
    h2 = fmaf(ap4.z, h2, he4.z);
    h3 = fmaf(ap4.w, h3, he4.w);
  }
  int t = b * SEQ + c * CHK;
  const float* dp = delta + (size_t)t * DI + d;
  const float* xp = xc + (size_t)t * DI + d;
  const float* bp = xdbl + (size_t)t * XD + DTR + ng * 4;
  const float* cp = xdbl + (size_t)t * XD + DTR + NST + ng * 4;
  const unsigned short* zp = xzb + (size_t)t * (2 * DI) + DI + d;
  unsigned short* yp = y + (size_t)t * DI + d;
  for (int l = 0; l < CHK; ++l) {
    float dv = *dp;
    float xv = *xp;
    float4 B4 = *(const float4*)bp;
    float4 C4 = *(const float4*)cp;
    float dx = dv * xv;
    float e0 = __expf(dv * a0), e1 = __expf(dv * a1);
    float e2 = __expf(dv * a2), e3 = __expf(dv * a3);
    h0 = fmaf(e0, h0, dx * B4.x);
    h1 = fmaf(e1, h1, dx * B4.y);
    h2 = fmaf(e2, h2, dx * B4.z);
    h3 = fmaf(e3, h3, dx * B4.w);
    float contrib = h0 * C4.x + h1 * C4.y + h2 * C4.z + h3 * C4.w;
    contrib += __shfl_xor(contrib, 1);
    contrib += __shfl_xor(contrib, 2);
    if (ng == 0) {
      float zv = b2f(*zp);
      float sig = zv / (1.f + __expf(-zv));
      *yp = f2b((contrib + xv * dskip) * sig);
    }
    dp += DI; xp += DI; bp += XD; cp += XD; zp += 2 * DI; yp += DI;
  }
}

// ---------------------------------------------------------------------------
extern "C" void kernel_launch(void* const* d_in, const int* in_sizes, int n_in,
                              void* d_out, int out_size, void* d_ws,
                              size_t ws_size, hipStream_t stream) {
  const float* x_in      = (const float*)d_in[0];
  const float* ln0_w     = (const float*)d_in[1];
  const float* ln0_b     = (const float*)d_in[2];
  const float* ln1_w     = (const float*)d_in[3];
  const float* ln1_b     = (const float*)d_in[4];
  const float* ln2_w     = (const float*)d_in[5];
  const float* ln2_b     = (const float*)d_in[6];
  const float* in_proj_w = (const float*)d_in[7];
  const float* conv_w    = (const float*)d_in[8];
  const float* conv_b    = (const float*)d_in[9];
  const float* x_proj_w  = (const float*)d_in[10];
  const float* dt_proj_w = (const float*)d_in[11];
  const float* dt_proj_b = (const float*)d_in[12];
  const float* A_log     = (const float*)d_in[13];
  const float* D_skip    = (const float*)d_in[14];
  const float* out_proj_w= (const float*)d_in[15];
  const float* ffn_w1    = (const float*)d_in[16];
  const float* ffn_b1    = (const float*)d_in[17];
  const float* ffn_w2    = (const float*)d_in[18];
  const float* ffn_b2    = (const float*)d_in[19];
  float* out = (float*)d_out;

  // Workspace layout (floats), liveness-aliased; total 20.12M floats = 80.5 MB
  float* ws    = (float*)d_ws;
  float* xws   = ws;                     // [T,DM] fp32 residual          2.097M
  float* big   = xws + 2097152;          // xzb bf16 [T,4096] / hbf bf16  4.194M
  float* r2    = big + 4194304;          // ybf bf16 [T,DI]               2.097M
  float* xcws  = r2 + 2097152;           // xc fp32 / bf16 split-K parts  4.194M
  float* xdbl  = xcws + 4194304;         // [T,96] fp32                   0.197M
  float* dws   = xdbl + 196608;          // xcb bf16 / delta fp32         4.194M
  float* ubf_f = dws + 4194304;          // [T,DM] bf16 LN out            1.049M
  float* wbf_f = ubf_f + 1048576;        // staging region                2.097M
  // aliases (timeline-checked):
  unsigned short* xzb  = (unsigned short*)big;   // in_proj out, dies after scan2
  unsigned short* hbf  = (unsigned short*)big;   // ffn1 -> ffn2 [T,FFN] bf16
  unsigned short* ybf  = (unsigned short*)r2;    // scan2 -> out_proj
  unsigned short* ubf  = (unsigned short*)ubf_f;
  unsigned short* xcb  = (unsigned short*)dws;   // conv bf16, dies before dt_proj
  unsigned short* pbf  = (unsigned short*)xcws;  // 4-layer bf16 partials [4][T,DM]
  unsigned short* wbf  = (unsigned short*)wbf_f;
  float* part  = wbf_f;                          // xproj partials [8][T,96] 1.573M
  unsigned short* wpb = (unsigned short*)(wbf_f + 1572864);  // x_proj_w bf16
  unsigned short* dtb = (unsigned short*)(wbf_f + 1671168);  // dt bf16 [T,64]
  unsigned short* dwb = (unsigned short*)(wbf_f + 1736704);  // dt_proj_w bf16
  // scan summaries overwrite the whole staging region after dt_proj:
  float* hend  = wbf_f;                  // [1048576] = B*NCHK*DI*NST
  float* aprod = wbf_f + 1048576;        // [1048576]

  // 1: convert in_proj_w -> bf16 (4096x1024)
  f2b_k<<<(4096 * 1024) / 1024, 256, 0, stream>>>(in_proj_w, wbf);
  // 2: fused LN0+LN1 -> xws fp32, ubf bf16
  ln01_k<<<T_TOK, 256, 0, stream>>>(x_in, ln0_w, ln0_b, ln1_w, ln1_b, xws, ubf);
  // 3: in_proj -> xzb bf16 (64x128 tiles, 1024 blocks)
  {
    dim3 g((2 * DI) / 128, T_TOK / 64);
    gemm64_k<<<g, 256, 0, stream>>>(ubf, DM, wbf, DM, xzb, 2 * DI, DM, 1, nullptr);
  }
  // 4: causal conv + silu (bf16 in) -> xc fp32 + xcb bf16
  conv_silu_k<<<(T_TOK * DI) / 256, 256, 0, stream>>>(xzb, conv_w, conv_b, xcws, xcb);
  // 5: x_proj + dt_proj weights -> bf16 (one dispatch)
  f2b2_k<<<(XD * DI + DI * DTR) / 1024, 256, 0, stream>>>(
      x_proj_w, wpb, (XD * DI) / 4, dt_proj_w, dwb);
  // 6: x_proj split-K MFMA + reduce -> xdbl fp32, dtb bf16
  {
    dim3 g(T_TOK / 64, SPLITK);
    xproj_k<<<g, 256, 0, stream>>>(xcb, wpb, part);
    xreduce_k<<<(T_TOK * XD) / 256, 256, 0, stream>>>(part, xdbl, dtb);
  }
  // 7: dt_proj + softplus (bf16 MFMA, 1 iter of BK=64) -> delta fp32
  {
    dim3 g(DI / 128, T_TOK / 128, 1);
    gemm_bf16<<<g, 256, 0, stream>>>(dtb, DTR, dwb, DTR, dws, DI, DTR, 5,
                                     dt_proj_b, nullptr);
  }
  // 8-9: chunked scan, 4 states/thread (summaries alias dead staging region)
  {
    int nthreads = 2 * NCHK * DI * 4;  // 262144
    scan1_k<<<nthreads / 256, 256, 0, stream>>>(dws, xcws, xdbl, A_log,
                                                hend, aprod);
    scan2_k<<<nthreads / 256, 256, 0, stream>>>(dws, xcws, xdbl, xzb,
                                                A_log, D_skip, hend, aprod, ybf);
  }
  // 10: out_proj split-K x4 (bf16 partials in pbf) + fused reduce+res+LN2
  f2b_k<<<(DM * DI) / 1024, 256, 0, stream>>>(out_proj_w, wbf);
  {
    dim3 g(DM / 128, T_TOK / 128, 4);
    gemm_bf16<<<g, 256, 0, stream>>>(ybf, DI, wbf, DI, nullptr, DM, DI / 4, 8,
                                     nullptr, pbf);
    reduce4lnb_k<<<T_TOK, 256, 0, stream>>>(pbf, xws, ln2_w, ln2_b, ubf);
  }
  // 11: ffn1 + bias + gelu -> hbf bf16 (64x128 tiles, 1024 blocks)
  f2b_k<<<(FFN * DM) / 1024, 256, 0, stream>>>(ffn_w1, wbf);
  {
    dim3 g(FFN / 128, T_TOK / 64);
    gemm64_k<<<g, 256, 0, stream>>>(ubf, DM, wbf, DM, hbf, FFN, DM, 2, ffn_b1);
  }
  // 12: ffn2 split-K x4 (bf16 partials in pbf) + reduce(+bias+res) -> d_out
  f2b_k<<<(DM * FFN) / 1024, 256, 0, stream>>>(ffn_w2, wbf);
  {
    dim3 g(DM / 128, T_TOK / 128, 4);
    gemm_bf16<<<g, 256, 0, stream>>>(hbf, FFN, wbf, FFN, nullptr, DM, FFN / 4, 8,
                                     nullptr, pbf);
    reduce4b_k<<<(T_TOK * DM) / 1024, 256, 0, stream>>>(pbf, out, ffn_b2, xws);
  }
}